// Round 16
// baseline (499.683 us; speedup 1.0000x reference)
//
#include <hip/hip_runtime.h>

#define NNODES 100000
#define EEDGES 600000
#define CDIM 128
#define HHEADS 2
#define DDIM 64
#define FIN 64
#define FOUT 8
#define NEG 0.2f

#define SB 200    // scan blocks
#define SCH 500   // nodes per scan block (200*500 = 100000 exactly)
#define SNB 384   // persistent score blocks per edge type

typedef _Float16 f16x8 __attribute__((ext_vector_type(8)));
typedef unsigned short ushort8 __attribute__((ext_vector_type(8)));
typedef float f32x4 __attribute__((ext_vector_type(4)));

__device__ __forceinline__ float tanh_fast(float x) {
    float e = __expf(2.f * x);
    return 1.f - 2.f / (e + 1.f);
}

__device__ __forceinline__ unsigned short f2h(float x) {
    _Float16 h = (_Float16)x;                 // RNE
    return __builtin_bit_cast(unsigned short, h);
}
__device__ __forceinline__ float h2f(unsigned short u) {
    return (float)__builtin_bit_cast(_Float16, u);
}
__device__ __forceinline__ float hrelu2f(unsigned short u) {
    return (u & 0x8000) ? 0.f : (float)__builtin_bit_cast(_Float16, u);
}

// 2-way semantic softmax from raw score sums (recomputed inline by consumers)
__device__ __forceinline__ void attn_from_sacc(const float* saccp, float& fa0, float& fa1) {
    float s0 = saccp[0] / (float)NNODES;
    float s1 = saccp[1] / (float)NNODES;
    float m = fmaxf(s0, s1);
    float e0 = expf(s0 - m), e1 = expf(s1 - m);
    float inv = 1.f / (e0 + e1);
    fa0 = e0 * inv; fa1 = e1 * inv;
}

// ---- ALL weight transposes (both layers) in one launch; also zeroes sacc[0..4) ----
__global__ __launch_bounds__(256)
void cvt_all(const float* __restrict__ p1w, const float* __restrict__ k1w,
             const float* __restrict__ p2w, const float* __restrict__ k2w,
             unsigned short* __restrict__ p1T, unsigned short* __restrict__ k1T,
             unsigned short* __restrict__ p2T, unsigned short* __restrict__ k2T,
             float* __restrict__ sacc) {
    int idx = blockIdx.x * 256 + threadIdx.x;
    if (blockIdx.x == 0 && threadIdx.x < 4) sacc[threadIdx.x] = 0.f;
    if (idx < FIN * CDIM) {                    // p1: [k][c] -> [c*FIN+k]
        int c = idx / FIN, k = idx % FIN;
        p1T[idx] = f2h(p1w[k * CDIM + c]);
    } else if (idx < (FIN + CDIM) * CDIM) {    // k1
        int j = idx - FIN * CDIM;
        int c = j >> 7, k = j & 127;
        k1T[j] = f2h(k1w[k * CDIM + c]);
    } else if (idx < (FIN + 2 * CDIM) * CDIM) { // p2
        int j = idx - (FIN + CDIM) * CDIM;
        int c = j >> 7, k = j & 127;
        p2T[j] = f2h(p2w[k * CDIM + c]);
    } else if (idx < (FIN + 3 * CDIM) * CDIM) { // k2
        int j = idx - (FIN + 2 * CDIM) * CDIM;
        int c = j >> 7, k = j & 127;
        k2T[j] = f2h(k2w[k * CDIM + c]);
    }
}

// ============ projection via MFMA (f16): H = f16(X@W + b), fused attention dots ============
// MODE 0: X f32 (layer 1). MODE 2: X = a0*relu(O0)+a1*relu(O1), attn from sacc (layer 2).
template<int K, int MODE>
__global__ __launch_bounds__(256)
void proj_mfma(const void* __restrict__ Xv, const void* __restrict__ Xv2,
               const float* __restrict__ saccp,
               const unsigned short* __restrict__ pwT_b,
               const float* __restrict__ bias,
               const float* __restrict__ att_src, const float* __restrict__ att_dst,
               unsigned short* __restrict__ Hout,
               float* __restrict__ a_src, float* __restrict__ a_dst) {
    const int U = K / 8;
    __shared__ ushort8 smem[192 * (K / 8)];   // As8 [64][U] + Bs8 [128][U]
    ushort8* As8 = smem;
    ushort8* Bs8 = smem + 64 * U;
    int tid = threadIdx.x;
    int row0 = blockIdx.x * 64;
    float fa0 = 0.f, fa1 = 0.f;
    if (MODE == 2) attn_from_sacc(saccp, fa0, fa1);

#pragma unroll
    for (int i = 0; i < (64 * U) / 256; ++i) {
        int idx = tid + i * 256;
        int row = idx / U, u = idx % U;
        int grow = row0 + row;
        ushort8 v;
        if (grow < NNODES) {
            if (MODE == 2) {
                ushort8 v0 = ((const ushort8*)Xv)[(long)grow * U + u];
                ushort8 v1 = ((const ushort8*)Xv2)[(long)grow * U + u];
#pragma unroll
                for (int e = 0; e < 8; ++e)
                    v[e] = f2h(fa0 * hrelu2f(v0[e]) + fa1 * hrelu2f(v1[e]));
            } else {
                const float* p = (const float*)Xv + (long)grow * K + u * 8;
                float4 a = *(const float4*)p;
                float4 b = *(const float4*)(p + 4);
                v[0] = f2h(a.x); v[1] = f2h(a.y); v[2] = f2h(a.z); v[3] = f2h(a.w);
                v[4] = f2h(b.x); v[5] = f2h(b.y); v[6] = f2h(b.z); v[7] = f2h(b.w);
            }
        } else v = (ushort8)0;
        As8[row * U + (u ^ (row & 7))] = v;
    }
#pragma unroll
    for (int i = 0; i < (128 * U) / 256; ++i) {
        int idx = tid + i * 256;
        int c = idx / U, u = idx % U;
        Bs8[c * U + (u ^ (c & 7))] = ((const ushort8*)pwT_b)[idx];
    }
    __syncthreads();

    int l = tid & 63, w = tid >> 6;
    int lrow = w * 16 + (l & 15);
    int ug = l >> 4;
    f32x4 acc[8];
#pragma unroll
    for (int ct = 0; ct < 8; ++ct) acc[ct] = (f32x4)0.f;

#pragma unroll
    for (int kc = 0; kc < K / 32; ++kc) {
        int u = kc * 4 + ug;
        f16x8 af = __builtin_bit_cast(f16x8, As8[lrow * U + (u ^ (lrow & 7))]);
#pragma unroll
        for (int ct = 0; ct < 8; ++ct) {
            int c = ct * 16 + (l & 15);
            f16x8 bf = __builtin_bit_cast(f16x8, Bs8[c * U + (u ^ (c & 7))]);
            acc[ct] = __builtin_amdgcn_mfma_f32_16x16x32_f16(af, bf, acc[ct], 0, 0, 0);
        }
    }

    __syncthreads();
    unsigned short* Cs = (unsigned short*)smem;  // [64][128]
#pragma unroll
    for (int ct = 0; ct < 8; ++ct) {
        int c = ct * 16 + (l & 15);
        float bc = bias[c];
#pragma unroll
        for (int v = 0; v < 4; ++v) {
            int rr = w * 16 + (l >> 4) * 4 + v;
            Cs[rr * 128 + c] = f2h(acc[ct][v] + bc);
        }
    }
    __syncthreads();

    int r = tid >> 2, q = tid & 3;
    int grow = row0 + r;
    if (grow < NNODES) {
        float h[32];
        ushort8 hv[4];
#pragma unroll
        for (int j = 0; j < 4; ++j) {
            hv[j] = *(ushort8*)&Cs[r * 128 + q * 32 + j * 8];
#pragma unroll
            for (int e = 0; e < 8; ++e) h[j * 8 + e] = h2f(hv[j][e]);
        }
#pragma unroll
        for (int j = 0; j < 4; ++j)
            *(ushort8*)(Hout + (long)grow * CDIM + q * 32 + j * 8) = hv[j];
#pragma unroll
        for (int i = 0; i < 2; ++i) {
            float s = 0.f, d = 0.f;
#pragma unroll
            for (int j = 0; j < 32; ++j) {
                s = fmaf(h[j], att_src[i * CDIM + q * 32 + j], s);
                d = fmaf(h[j], att_dst[i * CDIM + q * 32 + j], d);
            }
            s += __shfl_xor(s, 1, 64);
            d += __shfl_xor(d, 1, 64);
            if ((q & 1) == 0) {
                int hh = q >> 1;
                long base = (long)i * NNODES * HHEADS + (long)grow * HHEADS + hh;
                a_src[base] = s;
                a_dst[base] = d;
            }
        }
    }
}

// ---- semantic score via MFMA (f16): persistent blocks, kw staged ONCE ----
__global__ __launch_bounds__(256, 3)
void score_mfma_dual(const unsigned short* __restrict__ O0b,
                     const unsigned short* __restrict__ O1b,
                     const unsigned short* __restrict__ kwT_b,
                     const float* __restrict__ kb, const float* __restrict__ q,
                     float* __restrict__ sacc) {
    __shared__ ushort8 As8[64 * 16];    // 16 KB
    __shared__ ushort8 Bs8[128 * 16];   // 32 KB
    __shared__ float red[4];
    const int NT = (NNODES + 63) / 64;  // 1563 row tiles
    int bid = blockIdx.x;
    int type = bid >= SNB;
    const unsigned short* Omb = type ? O1b : O0b;
    int bt = bid - (type ? SNB : 0);
    int tid = threadIdx.x;

#pragma unroll
    for (int i = 0; i < 8; ++i) {
        int idx = tid + i * 256;
        int c = idx >> 4, u = idx & 15;
        Bs8[c * 16 + (u ^ (c & 7))] = ((const ushort8*)kwT_b)[idx];
    }

    int l = tid & 63, w = tid >> 6;
    int lrow = w * 16 + (l & 15);
    int ug = l >> 4;
    float s = 0.f;

    ushort8 pre[4];
    {
        int row0 = bt * 64;
#pragma unroll
        for (int i = 0; i < 4; ++i) {
            int idx = tid + i * 256;
            int row = idx >> 4, u = idx & 15;
            int grow = row0 + row;
            ushort8 v = (ushort8)0;
            if (bt < NT && grow < NNODES) {
                v = ((const ushort8*)Omb)[(long)grow * 16 + u];
#pragma unroll
                for (int e = 0; e < 8; ++e) v[e] = (v[e] & 0x8000) ? 0 : v[e];  // f16 relu
            }
            pre[i] = v;
        }
    }

    for (int t = bt; t < NT; t += SNB) {
        __syncthreads();
#pragma unroll
        for (int i = 0; i < 4; ++i) {
            int idx = tid + i * 256;
            int row = idx >> 4, u = idx & 15;
            As8[row * 16 + (u ^ (row & 7))] = pre[i];
        }
        int tn = t + SNB;
        if (tn < NT) {
            int row0n = tn * 64;
#pragma unroll
            for (int i = 0; i < 4; ++i) {
                int idx = tid + i * 256;
                int row = idx >> 4, u = idx & 15;
                int grow = row0n + row;
                ushort8 v = (ushort8)0;
                if (grow < NNODES) {
                    v = ((const ushort8*)Omb)[(long)grow * 16 + u];
#pragma unroll
                    for (int e = 0; e < 8; ++e) v[e] = (v[e] & 0x8000) ? 0 : v[e];
                }
                pre[i] = v;
            }
        }
        __syncthreads();

        f32x4 acc[8];
#pragma unroll
        for (int ct = 0; ct < 8; ++ct) acc[ct] = (f32x4)0.f;
#pragma unroll
        for (int kc = 0; kc < 4; ++kc) {
            int u = kc * 4 + ug;
            f16x8 af = __builtin_bit_cast(f16x8, As8[lrow * 16 + (u ^ (lrow & 7))]);
#pragma unroll
            for (int ct = 0; ct < 8; ++ct) {
                int c = ct * 16 + (l & 15);
                f16x8 bf = __builtin_bit_cast(f16x8, Bs8[c * 16 + (u ^ (c & 7))]);
                acc[ct] = __builtin_amdgcn_mfma_f32_16x16x32_f16(af, bf, acc[ct], 0, 0, 0);
            }
        }
        int row0 = t * 64;
#pragma unroll
        for (int ct = 0; ct < 8; ++ct) {
            int c = ct * 16 + (l & 15);
            float qc = q[c], kbc = kb[c];
#pragma unroll
            for (int v = 0; v < 4; ++v) {
                int grow = row0 + w * 16 + (l >> 4) * 4 + v;
                if (grow < NNODES) s += qc * tanh_fast(acc[ct][v] + kbc);
            }
        }
    }

#pragma unroll
    for (int m = 32; m >= 1; m >>= 1) s += __shfl_xor(s, m, 64);
    if (l == 0) red[w] = s;
    __syncthreads();
    if (tid == 0) atomicAdd(sacc + type, red[0] + red[1] + red[2] + red[3]);
}

// ============ CSR build (dual-type fused) ============
__global__ void hist_dual(const int* __restrict__ dst0, int* __restrict__ deg0,
                          const int* __restrict__ dst1, int* __restrict__ deg1, int gE) {
    int bid = blockIdx.x;
    int type = bid >= gE;
    const int* dst = type ? dst1 : dst0;
    int* deg = type ? deg1 : deg0;
    int e = (bid - (type ? gE : 0)) * 256 + threadIdx.x;
    if (e < EEDGES) atomicAdd(&deg[dst[e]], 1);
}

__global__ __launch_bounds__(256)
void scan_partial_dual(const int* __restrict__ deg0, int* __restrict__ bsum0,
                       const int* __restrict__ deg1, int* __restrict__ bsum1) {
    __shared__ int red[256];
    int bid = blockIdx.x;
    int type = bid >= SB;
    const int* deg = type ? deg1 : deg0;
    int* bsum = type ? bsum1 : bsum0;
    int b = bid - (type ? SB : 0), t = threadIdx.x;
    int s = 0;
    if (t < 250) {
        int base = b * SCH + t * 2;
        s = deg[base] + deg[base + 1];
    }
    red[t] = s;
    __syncthreads();
#pragma unroll
    for (int off = 128; off >= 1; off >>= 1) {
        if (t < off) red[t] += red[t + off];
        __syncthreads();
    }
    if (t == 0) bsum[b] = red[0];
}

__global__ void scan_bsum_dual(int* __restrict__ bsum0, int* __restrict__ bsum1) {
    int t = threadIdx.x;
    if (t < 2) {
        int* bsum = t ? bsum1 : bsum0;
        int run = 0;
        for (int i = 0; i < SB; ++i) { int v = bsum[i]; bsum[i] = run; run += v; }
    }
}

// writes rowptr AND cursor (removes the cursor memcpy dispatch)
__global__ __launch_bounds__(256)
void scan_final_dual(const int* __restrict__ deg0, const int* __restrict__ bsum0,
                     int* __restrict__ rowptr0, int* __restrict__ cursor0,
                     const int* __restrict__ deg1, const int* __restrict__ bsum1,
                     int* __restrict__ rowptr1, int* __restrict__ cursor1) {
    __shared__ int ts[256];
    int bid = blockIdx.x;
    int type = bid >= SB;
    const int* deg = type ? deg1 : deg0;
    const int* bsum = type ? bsum1 : bsum0;
    int* rowptr = type ? rowptr1 : rowptr0;
    int* cursor = type ? cursor1 : cursor0;
    int b = bid - (type ? SB : 0), t = threadIdx.x;
    int d0 = 0, d1 = 0;
    int base = b * SCH + t * 2;
    if (t < 250) { d0 = deg[base]; d1 = deg[base + 1]; }
    ts[t] = d0 + d1;
    __syncthreads();
#pragma unroll
    for (int off = 1; off < 256; off <<= 1) {
        int v = (t >= off) ? ts[t - off] : 0;
        __syncthreads();
        ts[t] += v;
        __syncthreads();
    }
    if (t < 250) {
        int excl = bsum[b] + (t > 0 ? ts[t - 1] : 0);
        rowptr[base] = excl;      cursor[base] = excl;
        rowptr[base + 1] = excl + d0;  cursor[base + 1] = excl + d0;
    }
    if (b == 0 && t == 0) rowptr[NNODES] = EEDGES;
}

__global__ void fill_dual(const int* __restrict__ src0, const int* __restrict__ dst0,
                          int* __restrict__ cur0, int* __restrict__ cs0,
                          const int* __restrict__ src1, const int* __restrict__ dst1,
                          int* __restrict__ cur1, int* __restrict__ cs1, int gE) {
    int bid = blockIdx.x;
    int type = bid >= gE;
    const int* src = type ? src1 : src0;
    const int* dst = type ? dst1 : dst0;
    int* cursor = type ? cur1 : cur0;
    int* csr_src = type ? cs1 : cs0;
    int e = (bid - (type ? gE : 0)) * 256 + threadIdx.x;
    if (e < EEDGES) {
        int pos = atomicAdd(&cursor[dst[e]], 1);
        csr_src[pos] = src[e];
    }
}

// ============ single-pass aggregation v6: quad-gather + f16 (v_fma_mix) ============
__global__ __launch_bounds__(256)
void seg_aggregate_dual(const int* __restrict__ rp0, const int* __restrict__ cs0,
                        const float* __restrict__ as0, const float* __restrict__ ad0,
                        unsigned short* __restrict__ O0,
                        const int* __restrict__ rp1, const int* __restrict__ cs1,
                        const float* __restrict__ as1, const float* __restrict__ ad1,
                        unsigned short* __restrict__ O1,
                        const unsigned short* __restrict__ Hfeat, int gseg) {
    int bid = blockIdx.x;
    int type = bid >= gseg;
    const int* rowptr = type ? rp1 : rp0;
    const int* csr_src = type ? cs1 : cs0;
    const float* asv = type ? as1 : as0;
    const float* adv = type ? ad1 : ad0;
    unsigned short* Out = type ? O1 : O0;
    int node = (bid - (type ? gseg : 0)) * 4 + (threadIdx.x >> 6);
    if (node >= NNODES) return;
    int lane = threadIdx.x & 63;
    int rowgrp = lane >> 4;      // which edge of the quad this lane serves
    int cpos = lane & 15;        // channel block: channels cpos*8 .. cpos*8+7
    int start = rowptr[node], end = rowptr[node + 1];
    int deg = end - start;
    float2 adn = *(const float2*)(adv + node * 2);

    float a[8] = {0.f, 0.f, 0.f, 0.f, 0.f, 0.f, 0.f, 0.f};
    float s0 = 0.f, s1 = 0.f;
    for (int base = 0; base < deg; base += 64) {
        int n = deg - base; if (n > 64) n = 64;
        // stage: lane i computes edge base+i's weight (coalesced csr load + as gather + exp)
        int sA = 0; float wx = 0.f, wy = 0.f;
        if (lane < n) {
            sA = csr_src[start + base + lane];
            float2 av = *(const float2*)(asv + sA * 2);
            float r0 = av.x + adn.x; r0 = r0 >= 0.f ? r0 : NEG * r0;
            float r1 = av.y + adn.y; r1 = r1 >= 0.f ? r1 : NEG * r1;
            wx = __expf(r0); wy = __expf(r1);
        }
        s0 += wx; s1 += wy;
        for (int e0 = 0; e0 < n; e0 += 8) {
            // quad A: edges e0..e0+3 (padding lanes hold w=0, si=0)
            int eA = e0 + rowgrp;
            int siA = __shfl(sA, eA, 64);
            float wxA = __shfl(wx, eA, 64);
            float wyA = __shfl(wy, eA, 64);
            float wA = cpos < 8 ? wxA : wyA;
            uint4 rhA = *(const uint4*)(Hfeat + (long)siA * CDIM + cpos * 8);
            f16x8 hA = __builtin_bit_cast(f16x8, rhA);
#pragma unroll
            for (int i = 0; i < 8; ++i) a[i] = fmaf((float)hA[i], wA, a[i]);
            if (e0 + 4 < n) {  // wave-uniform: quad B edges e0+4..e0+7
                int eB = e0 + 4 + rowgrp;
                int siB = __shfl(sA, eB, 64);
                float wxB = __shfl(wx, eB, 64);
                float wyB = __shfl(wy, eB, 64);
                float wB = cpos < 8 ? wxB : wyB;
                uint4 rhB = *(const uint4*)(Hfeat + (long)siB * CDIM + cpos * 8);
                f16x8 hB = __builtin_bit_cast(f16x8, rhB);
#pragma unroll
                for (int i = 0; i < 8; ++i) a[i] = fmaf((float)hB[i], wB, a[i]);
            }
        }
    }
    // softmax denominators over all lanes
#pragma unroll
    for (int m = 32; m >= 1; m >>= 1) {
        s0 += __shfl_xor(s0, m, 64);
        s1 += __shfl_xor(s1, m, 64);
    }
    // merge the 4 edge-groups (rowgrp dimension = lane bits 4,5)
#pragma unroll
    for (int i = 0; i < 8; ++i) {
        a[i] += __shfl_xor(a[i], 16, 64);
        a[i] += __shfl_xor(a[i], 32, 64);
    }
    if (lane < 16) {
        float ssel = cpos < 8 ? s0 : s1;
        float inv = ssel > 0.f ? 1.f / ssel : 0.f;
        uint4 o;
        o.x = (unsigned int)f2h(a[0] * inv) | ((unsigned int)f2h(a[1] * inv) << 16);
        o.y = (unsigned int)f2h(a[2] * inv) | ((unsigned int)f2h(a[3] * inv) << 16);
        o.z = (unsigned int)f2h(a[4] * inv) | ((unsigned int)f2h(a[5] * inv) << 16);
        o.w = (unsigned int)f2h(a[6] * inv) | ((unsigned int)f2h(a[7] * inv) << 16);
        *(uint4*)(Out + (long)node * CDIM + cpos * 8) = o;
    }
}

// ---- final classifier with fused semantic combine (attn computed inline) ----
__global__ __launch_bounds__(256)
void final_linear_kernel(const unsigned short* __restrict__ O0,
                         const unsigned short* __restrict__ O1,
                         const float* __restrict__ saccp,
                         const float* __restrict__ lw, const float* __restrict__ lb,
                         float* __restrict__ out) {
    __shared__ float lws[CDIM * FOUT];
    int tid = threadIdx.x;
    for (int i = tid; i < CDIM * FOUT; i += 256) lws[i] = lw[i];
    __syncthreads();
    float fa0, fa1;
    attn_from_sacc(saccp, fa0, fa1);
    int idx = blockIdx.x * 256 + tid;
    if (idx >= NNODES * FOUT) return;
    int n = idx >> 3, o = idx & 7;
    const ushort8* r0 = (const ushort8*)(O0 + (long)n * CDIM);
    const ushort8* r1 = (const ushort8*)(O1 + (long)n * CDIM);
    float acc = lb[o];
#pragma unroll
    for (int k8 = 0; k8 < 16; ++k8) {
        ushort8 v0 = r0[k8];
        ushort8 v1 = r1[k8];
#pragma unroll
        for (int e = 0; e < 8; ++e) {
            float hv = fa0 * hrelu2f(v0[e]) + fa1 * hrelu2f(v1[e]);
            acc = fmaf(hv, lws[(k8 * 8 + e) * FOUT + o], acc);
        }
    }
    out[idx] = acc;
}

extern "C" void kernel_launch(void* const* d_in, const int* in_sizes, int n_in,
                              void* d_out, int out_size, void* d_ws, size_t ws_size,
                              hipStream_t stream) {
    const float* x          = (const float*)d_in[0];
    const int*   ei_spatial = (const int*)d_in[1];
    const int*   ei_similar = (const int*)d_in[2];
    const float* p1_proj_w  = (const float*)d_in[3];
    const float* p1_proj_b  = (const float*)d_in[4];
    const float* p1_att_src = (const float*)d_in[5];
    const float* p1_att_dst = (const float*)d_in[6];
    const float* p1_q       = (const float*)d_in[7];
    const float* p1_kw      = (const float*)d_in[8];
    const float* p1_kb      = (const float*)d_in[9];
    const float* p2_proj_w  = (const float*)d_in[10];
    const float* p2_proj_b  = (const float*)d_in[11];
    const float* p2_att_src = (const float*)d_in[12];
    const float* p2_att_dst = (const float*)d_in[13];
    const float* p2_q       = (const float*)d_in[14];
    const float* p2_kw      = (const float*)d_in[15];
    const float* p2_kb      = (const float*)d_in[16];
    const float* lin_w      = (const float*)d_in[17];
    const float* lin_b      = (const float*)d_in[18];

    float* ws = (float*)d_ws;
    const size_t nc = (size_t)NNODES * CDIM;
    const size_t nh2 = (size_t)NNODES * HHEADS;

    float* asrc = ws;                    // 2*N*H
    float* adst = asrc + 2 * nh2;        // 2*N*H
    float* sacc = adst + 2 * nh2;        // 4 (L1: [0..1], L2: [2..3])
    int* rowptr0 = (int*)(sacc + 4);     // N+1
    int* rowptr1 = rowptr0 + (NNODES + 1);
    int* cursor0 = rowptr1 + (NNODES + 1);  // N+1
    int* cursor1 = cursor0 + (NNODES + 1);
    int* cs0     = cursor1 + (NNODES + 1);  // E
    int* cs1     = cs0 + EEDGES;            // E
    int* deg0    = cs1 + EEDGES;            // N (deg0/deg1 contiguous for one memset)
    int* deg1    = deg0 + NNODES;           // N
    int* bsum0   = deg1 + NNODES;           // SB
    int* bsum1   = bsum0 + SB;              // SB
    uintptr_t kp = (uintptr_t)(bsum1 + SB);
    kp = (kp + 15) & ~(uintptr_t)15;
    unsigned short* p1T = (unsigned short*)kp;      // FIN*CDIM f16
    unsigned short* k1T = p1T + FIN * CDIM;         // CDIM*CDIM
    unsigned short* p2T = k1T + CDIM * CDIM;        // CDIM*CDIM
    unsigned short* k2T = p2T + CDIM * CDIM;        // CDIM*CDIM
    unsigned short* Hb  = k2T + CDIM * CDIM;        // N*C f16
    unsigned short* O0b = Hb + nc;
    unsigned short* O1b = O0b + nc;

    const int gE = (EEDGES + 255) / 256;
    const int gm = (NNODES + 63) / 64;      // 1563
    const int gseg = (NNODES + 3) / 4;
    const int nh = NNODES * HHEADS;

    // ---- build CSR for both edge types (structure reused across layers) ----
    hipMemsetAsync(deg0, 0, 2 * NNODES * sizeof(int), stream);
    hist_dual<<<2 * gE, 256, 0, stream>>>(ei_spatial + EEDGES, deg0,
                                          ei_similar + EEDGES, deg1, gE);
    scan_partial_dual<<<2 * SB, 256, 0, stream>>>(deg0, bsum0, deg1, bsum1);
    scan_bsum_dual<<<1, 64, 0, stream>>>(bsum0, bsum1);
    scan_final_dual<<<2 * SB, 256, 0, stream>>>(deg0, bsum0, rowptr0, cursor0,
                                                deg1, bsum1, rowptr1, cursor1);
    fill_dual<<<2 * gE, 256, 0, stream>>>(ei_spatial, ei_spatial + EEDGES, cursor0, cs0,
                                          ei_similar, ei_similar + EEDGES, cursor1, cs1, gE);

    // ---- all weight transposes (both layers) + sacc zero, one dispatch ----
    const int cvtN = (FIN + 3 * CDIM) * CDIM;
    cvt_all<<<(cvtN + 255) / 256, 256, 0, stream>>>(
        p1_proj_w, p1_kw, p2_proj_w, p2_kw, p1T, k1T, p2T, k2T, sacc);

    // ================= Layer 1 =================
    proj_mfma<FIN, 0><<<gm, 256, 0, stream>>>(x, nullptr, nullptr, p1T, p1_proj_b,
                                              p1_att_src, p1_att_dst, Hb, asrc, adst);
    seg_aggregate_dual<<<2 * gseg, 256, 0, stream>>>(
        rowptr0, cs0, asrc, adst, O0b,
        rowptr1, cs1, asrc + nh, adst + nh, O1b, Hb, gseg);
    score_mfma_dual<<<2 * SNB, 256, 0, stream>>>(O0b, O1b, k1T, p1_kb, p1_q, sacc);

    // ================= Layer 2 (combine + attn-softmax fused into proj) =================
    proj_mfma<CDIM, 2><<<gm, 256, 0, stream>>>(O0b, O1b, sacc, p2T, p2_proj_b,
                                               p2_att_src, p2_att_dst, Hb, asrc, adst);
    seg_aggregate_dual<<<2 * gseg, 256, 0, stream>>>(
        rowptr0, cs0, asrc, adst, O0b,
        rowptr1, cs1, asrc + nh, adst + nh, O1b, Hb, gseg);
    score_mfma_dual<<<2 * SNB, 256, 0, stream>>>(O0b, O1b, k2T, p2_kb, p2_q, sacc + 2);

    // ================= Final classifier (combine + attn-softmax fused) =================
    const int gfin = (NNODES * FOUT + 255) / 256;
    final_linear_kernel<<<gfin, 256, 0, stream>>>(O0b, O1b, sacc + 2, lin_w, lin_b,
                                                  (float*)d_out);
}

// Round 17
// 476.958 us; speedup vs baseline: 1.0476x; 1.0476x over previous
//
#include <hip/hip_runtime.h>

#define NNODES 100000
#define EEDGES 600000
#define CDIM 128
#define HHEADS 2
#define DDIM 64
#define FIN 64
#define FOUT 8
#define NEG 0.2f

#define SB 200    // scan blocks
#define SCH 500   // nodes per scan block (200*500 = 100000 exactly)
#define SNB 384   // persistent score blocks per edge type

typedef _Float16 f16x8 __attribute__((ext_vector_type(8)));
typedef unsigned short ushort8 __attribute__((ext_vector_type(8)));
typedef float f32x4 __attribute__((ext_vector_type(4)));

__device__ __forceinline__ float tanh_fast(float x) {
    float e = __expf(2.f * x);
    return 1.f - 2.f / (e + 1.f);
}

__device__ __forceinline__ unsigned short f2h(float x) {
    _Float16 h = (_Float16)x;                 // RNE
    return __builtin_bit_cast(unsigned short, h);
}
__device__ __forceinline__ float h2f(unsigned short u) {
    return (float)__builtin_bit_cast(_Float16, u);
}
__device__ __forceinline__ float hrelu2f(unsigned short u) {
    return (u & 0x8000) ? 0.f : (float)__builtin_bit_cast(_Float16, u);
}

// 2-way semantic softmax from raw score sums (recomputed inline by consumers)
__device__ __forceinline__ void attn_from_sacc(const float* saccp, float& fa0, float& fa1) {
    float s0 = saccp[0] / (float)NNODES;
    float s1 = saccp[1] / (float)NNODES;
    float m = fmaxf(s0, s1);
    float e0 = expf(s0 - m), e1 = expf(s1 - m);
    float inv = 1.f / (e0 + e1);
    fa0 = e0 * inv; fa1 = e1 * inv;
}

// ---- ALL weight transposes (both layers) in one launch; also zeroes sacc[0..4) ----
__global__ __launch_bounds__(256)
void cvt_all(const float* __restrict__ p1w, const float* __restrict__ k1w,
             const float* __restrict__ p2w, const float* __restrict__ k2w,
             unsigned short* __restrict__ p1T, unsigned short* __restrict__ k1T,
             unsigned short* __restrict__ p2T, unsigned short* __restrict__ k2T,
             float* __restrict__ sacc) {
    int idx = blockIdx.x * 256 + threadIdx.x;
    if (blockIdx.x == 0 && threadIdx.x < 4) sacc[threadIdx.x] = 0.f;
    if (idx < FIN * CDIM) {                    // p1: [k][c] -> [c*FIN+k]
        int c = idx / FIN, k = idx % FIN;
        p1T[idx] = f2h(p1w[k * CDIM + c]);
    } else if (idx < (FIN + CDIM) * CDIM) {    // k1
        int j = idx - FIN * CDIM;
        int c = j >> 7, k = j & 127;
        k1T[j] = f2h(k1w[k * CDIM + c]);
    } else if (idx < (FIN + 2 * CDIM) * CDIM) { // p2
        int j = idx - (FIN + CDIM) * CDIM;
        int c = j >> 7, k = j & 127;
        p2T[j] = f2h(p2w[k * CDIM + c]);
    } else if (idx < (FIN + 3 * CDIM) * CDIM) { // k2
        int j = idx - (FIN + 2 * CDIM) * CDIM;
        int c = j >> 7, k = j & 127;
        k2T[j] = f2h(k2w[k * CDIM + c]);
    }
}

// ============ projection via MFMA (f16): H = f16(X@W + b), fused attention dots ============
// MODE 0: X f32 (layer 1). MODE 2: X = a0*relu(O0)+a1*relu(O1), attn from sacc (layer 2).
template<int K, int MODE>
__global__ __launch_bounds__(256)
void proj_mfma(const void* __restrict__ Xv, const void* __restrict__ Xv2,
               const float* __restrict__ saccp,
               const unsigned short* __restrict__ pwT_b,
               const float* __restrict__ bias,
               const float* __restrict__ att_src, const float* __restrict__ att_dst,
               unsigned short* __restrict__ Hout,
               float* __restrict__ a_src, float* __restrict__ a_dst) {
    const int U = K / 8;
    __shared__ ushort8 smem[192 * (K / 8)];   // As8 [64][U] + Bs8 [128][U]
    ushort8* As8 = smem;
    ushort8* Bs8 = smem + 64 * U;
    int tid = threadIdx.x;
    int row0 = blockIdx.x * 64;
    float fa0 = 0.f, fa1 = 0.f;
    if (MODE == 2) attn_from_sacc(saccp, fa0, fa1);

#pragma unroll
    for (int i = 0; i < (64 * U) / 256; ++i) {
        int idx = tid + i * 256;
        int row = idx / U, u = idx % U;
        int grow = row0 + row;
        ushort8 v;
        if (grow < NNODES) {
            if (MODE == 2) {
                ushort8 v0 = ((const ushort8*)Xv)[(long)grow * U + u];
                ushort8 v1 = ((const ushort8*)Xv2)[(long)grow * U + u];
#pragma unroll
                for (int e = 0; e < 8; ++e)
                    v[e] = f2h(fa0 * hrelu2f(v0[e]) + fa1 * hrelu2f(v1[e]));
            } else {
                const float* p = (const float*)Xv + (long)grow * K + u * 8;
                float4 a = *(const float4*)p;
                float4 b = *(const float4*)(p + 4);
                v[0] = f2h(a.x); v[1] = f2h(a.y); v[2] = f2h(a.z); v[3] = f2h(a.w);
                v[4] = f2h(b.x); v[5] = f2h(b.y); v[6] = f2h(b.z); v[7] = f2h(b.w);
            }
        } else v = (ushort8)0;
        As8[row * U + (u ^ (row & 7))] = v;
    }
#pragma unroll
    for (int i = 0; i < (128 * U) / 256; ++i) {
        int idx = tid + i * 256;
        int c = idx / U, u = idx % U;
        Bs8[c * U + (u ^ (c & 7))] = ((const ushort8*)pwT_b)[idx];
    }
    __syncthreads();

    int l = tid & 63, w = tid >> 6;
    int lrow = w * 16 + (l & 15);
    int ug = l >> 4;
    f32x4 acc[8];
#pragma unroll
    for (int ct = 0; ct < 8; ++ct) acc[ct] = (f32x4)0.f;

#pragma unroll
    for (int kc = 0; kc < K / 32; ++kc) {
        int u = kc * 4 + ug;
        f16x8 af = __builtin_bit_cast(f16x8, As8[lrow * U + (u ^ (lrow & 7))]);
#pragma unroll
        for (int ct = 0; ct < 8; ++ct) {
            int c = ct * 16 + (l & 15);
            f16x8 bf = __builtin_bit_cast(f16x8, Bs8[c * U + (u ^ (c & 7))]);
            acc[ct] = __builtin_amdgcn_mfma_f32_16x16x32_f16(af, bf, acc[ct], 0, 0, 0);
        }
    }

    __syncthreads();
    unsigned short* Cs = (unsigned short*)smem;  // [64][128]
#pragma unroll
    for (int ct = 0; ct < 8; ++ct) {
        int c = ct * 16 + (l & 15);
        float bc = bias[c];
#pragma unroll
        for (int v = 0; v < 4; ++v) {
            int rr = w * 16 + (l >> 4) * 4 + v;
            Cs[rr * 128 + c] = f2h(acc[ct][v] + bc);
        }
    }
    __syncthreads();

    int r = tid >> 2, q = tid & 3;
    int grow = row0 + r;
    if (grow < NNODES) {
        float h[32];
        ushort8 hv[4];
#pragma unroll
        for (int j = 0; j < 4; ++j) {
            hv[j] = *(ushort8*)&Cs[r * 128 + q * 32 + j * 8];
#pragma unroll
            for (int e = 0; e < 8; ++e) h[j * 8 + e] = h2f(hv[j][e]);
        }
#pragma unroll
        for (int j = 0; j < 4; ++j)
            *(ushort8*)(Hout + (long)grow * CDIM + q * 32 + j * 8) = hv[j];
#pragma unroll
        for (int i = 0; i < 2; ++i) {
            float s = 0.f, d = 0.f;
#pragma unroll
            for (int j = 0; j < 32; ++j) {
                s = fmaf(h[j], att_src[i * CDIM + q * 32 + j], s);
                d = fmaf(h[j], att_dst[i * CDIM + q * 32 + j], d);
            }
            s += __shfl_xor(s, 1, 64);
            d += __shfl_xor(d, 1, 64);
            if ((q & 1) == 0) {
                int hh = q >> 1;
                long base = (long)i * NNODES * HHEADS + (long)grow * HHEADS + hh;
                a_src[base] = s;
                a_dst[base] = d;
            }
        }
    }
}

// ---- semantic score via MFMA (f16): persistent blocks, kw staged ONCE ----
__global__ __launch_bounds__(256, 3)
void score_mfma_dual(const unsigned short* __restrict__ O0b,
                     const unsigned short* __restrict__ O1b,
                     const unsigned short* __restrict__ kwT_b,
                     const float* __restrict__ kb, const float* __restrict__ q,
                     float* __restrict__ sacc) {
    __shared__ ushort8 As8[64 * 16];    // 16 KB
    __shared__ ushort8 Bs8[128 * 16];   // 32 KB
    __shared__ float red[4];
    const int NT = (NNODES + 63) / 64;  // 1563 row tiles
    int bid = blockIdx.x;
    int type = bid >= SNB;
    const unsigned short* Omb = type ? O1b : O0b;
    int bt = bid - (type ? SNB : 0);
    int tid = threadIdx.x;

#pragma unroll
    for (int i = 0; i < 8; ++i) {
        int idx = tid + i * 256;
        int c = idx >> 4, u = idx & 15;
        Bs8[c * 16 + (u ^ (c & 7))] = ((const ushort8*)kwT_b)[idx];
    }

    int l = tid & 63, w = tid >> 6;
    int lrow = w * 16 + (l & 15);
    int ug = l >> 4;
    float s = 0.f;

    ushort8 pre[4];
    {
        int row0 = bt * 64;
#pragma unroll
        for (int i = 0; i < 4; ++i) {
            int idx = tid + i * 256;
            int row = idx >> 4, u = idx & 15;
            int grow = row0 + row;
            ushort8 v = (ushort8)0;
            if (bt < NT && grow < NNODES) {
                v = ((const ushort8*)Omb)[(long)grow * 16 + u];
#pragma unroll
                for (int e = 0; e < 8; ++e) v[e] = (v[e] & 0x8000) ? 0 : v[e];  // f16 relu
            }
            pre[i] = v;
        }
    }

    for (int t = bt; t < NT; t += SNB) {
        __syncthreads();
#pragma unroll
        for (int i = 0; i < 4; ++i) {
            int idx = tid + i * 256;
            int row = idx >> 4, u = idx & 15;
            As8[row * 16 + (u ^ (row & 7))] = pre[i];
        }
        int tn = t + SNB;
        if (tn < NT) {
            int row0n = tn * 64;
#pragma unroll
            for (int i = 0; i < 4; ++i) {
                int idx = tid + i * 256;
                int row = idx >> 4, u = idx & 15;
                int grow = row0n + row;
                ushort8 v = (ushort8)0;
                if (grow < NNODES) {
                    v = ((const ushort8*)Omb)[(long)grow * 16 + u];
#pragma unroll
                    for (int e = 0; e < 8; ++e) v[e] = (v[e] & 0x8000) ? 0 : v[e];
                }
                pre[i] = v;
            }
        }
        __syncthreads();

        f32x4 acc[8];
#pragma unroll
        for (int ct = 0; ct < 8; ++ct) acc[ct] = (f32x4)0.f;
#pragma unroll
        for (int kc = 0; kc < 4; ++kc) {
            int u = kc * 4 + ug;
            f16x8 af = __builtin_bit_cast(f16x8, As8[lrow * 16 + (u ^ (lrow & 7))]);
#pragma unroll
            for (int ct = 0; ct < 8; ++ct) {
                int c = ct * 16 + (l & 15);
                f16x8 bf = __builtin_bit_cast(f16x8, Bs8[c * 16 + (u ^ (c & 7))]);
                acc[ct] = __builtin_amdgcn_mfma_f32_16x16x32_f16(af, bf, acc[ct], 0, 0, 0);
            }
        }
        int row0 = t * 64;
#pragma unroll
        for (int ct = 0; ct < 8; ++ct) {
            int c = ct * 16 + (l & 15);
            float qc = q[c], kbc = kb[c];
#pragma unroll
            for (int v = 0; v < 4; ++v) {
                int grow = row0 + w * 16 + (l >> 4) * 4 + v;
                if (grow < NNODES) s += qc * tanh_fast(acc[ct][v] + kbc);
            }
        }
    }

#pragma unroll
    for (int m = 32; m >= 1; m >>= 1) s += __shfl_xor(s, m, 64);
    if (l == 0) red[w] = s;
    __syncthreads();
    if (tid == 0) atomicAdd(sacc + type, red[0] + red[1] + red[2] + red[3]);
}

// ============ CSR build (dual-type fused) ============
__global__ void hist_dual(const int* __restrict__ dst0, int* __restrict__ deg0,
                          const int* __restrict__ dst1, int* __restrict__ deg1, int gE) {
    int bid = blockIdx.x;
    int type = bid >= gE;
    const int* dst = type ? dst1 : dst0;
    int* deg = type ? deg1 : deg0;
    int e = (bid - (type ? gE : 0)) * 256 + threadIdx.x;
    if (e < EEDGES) atomicAdd(&deg[dst[e]], 1);
}

__global__ __launch_bounds__(256)
void scan_partial_dual(const int* __restrict__ deg0, int* __restrict__ bsum0,
                       const int* __restrict__ deg1, int* __restrict__ bsum1) {
    __shared__ int red[256];
    int bid = blockIdx.x;
    int type = bid >= SB;
    const int* deg = type ? deg1 : deg0;
    int* bsum = type ? bsum1 : bsum0;
    int b = bid - (type ? SB : 0), t = threadIdx.x;
    int s = 0;
    if (t < 250) {
        int base = b * SCH + t * 2;
        s = deg[base] + deg[base + 1];
    }
    red[t] = s;
    __syncthreads();
#pragma unroll
    for (int off = 128; off >= 1; off >>= 1) {
        if (t < off) red[t] += red[t + off];
        __syncthreads();
    }
    if (t == 0) bsum[b] = red[0];
}

__global__ void scan_bsum_dual(int* __restrict__ bsum0, int* __restrict__ bsum1) {
    int t = threadIdx.x;
    if (t < 2) {
        int* bsum = t ? bsum1 : bsum0;
        int run = 0;
        for (int i = 0; i < SB; ++i) { int v = bsum[i]; bsum[i] = run; run += v; }
    }
}

// writes rowptr AND cursor (removes the cursor memcpy dispatch)
__global__ __launch_bounds__(256)
void scan_final_dual(const int* __restrict__ deg0, const int* __restrict__ bsum0,
                     int* __restrict__ rowptr0, int* __restrict__ cursor0,
                     const int* __restrict__ deg1, const int* __restrict__ bsum1,
                     int* __restrict__ rowptr1, int* __restrict__ cursor1) {
    __shared__ int ts[256];
    int bid = blockIdx.x;
    int type = bid >= SB;
    const int* deg = type ? deg1 : deg0;
    const int* bsum = type ? bsum1 : bsum0;
    int* rowptr = type ? rowptr1 : rowptr0;
    int* cursor = type ? cursor1 : cursor0;
    int b = bid - (type ? SB : 0), t = threadIdx.x;
    int d0 = 0, d1 = 0;
    int base = b * SCH + t * 2;
    if (t < 250) { d0 = deg[base]; d1 = deg[base + 1]; }
    ts[t] = d0 + d1;
    __syncthreads();
#pragma unroll
    for (int off = 1; off < 256; off <<= 1) {
        int v = (t >= off) ? ts[t - off] : 0;
        __syncthreads();
        ts[t] += v;
        __syncthreads();
    }
    if (t < 250) {
        int excl = bsum[b] + (t > 0 ? ts[t - 1] : 0);
        rowptr[base] = excl;      cursor[base] = excl;
        rowptr[base + 1] = excl + d0;  cursor[base + 1] = excl + d0;
    }
    if (b == 0 && t == 0) rowptr[NNODES] = EEDGES;
}

__global__ void fill_dual(const int* __restrict__ src0, const int* __restrict__ dst0,
                          int* __restrict__ cur0, int* __restrict__ cs0,
                          const int* __restrict__ src1, const int* __restrict__ dst1,
                          int* __restrict__ cur1, int* __restrict__ cs1, int gE) {
    int bid = blockIdx.x;
    int type = bid >= gE;
    const int* src = type ? src1 : src0;
    const int* dst = type ? dst1 : dst0;
    int* cursor = type ? cur1 : cur0;
    int* csr_src = type ? cs1 : cs0;
    int e = (bid - (type ? gE : 0)) * 256 + threadIdx.x;
    if (e < EEDGES) {
        int pos = atomicAdd(&cursor[dst[e]], 1);
        csr_src[pos] = src[e];
    }
}

// ============ single-pass aggregation v7: 16-lane group per node ============
// Wave = 4 nodes (one per 16-lane group); lane covers 8 f16 channels (cpos*8..+7).
// Per edge: group-uniform broadcast loads (csr, as), redundant in-group weight exp,
// per-lane uint4 gather (one wave instr = 4 edge rows, 1 KB). No shuffles, no
// reductions: s is group-uniform, channels exclusively owned.
// 100000 = 6250*16 exactly -> no bounds checks.
__global__ __launch_bounds__(256)
void seg_aggregate_dual(const int* __restrict__ rp0, const int* __restrict__ cs0,
                        const float* __restrict__ as0, const float* __restrict__ ad0,
                        unsigned short* __restrict__ O0,
                        const int* __restrict__ rp1, const int* __restrict__ cs1,
                        const float* __restrict__ as1, const float* __restrict__ ad1,
                        unsigned short* __restrict__ O1,
                        const unsigned short* __restrict__ Hfeat, int gseg) {
    int bid = blockIdx.x;
    int type = bid >= gseg;
    const int* rowptr = type ? rp1 : rp0;
    const int* csr_src = type ? cs1 : cs0;
    const float* asv = type ? as1 : as0;
    const float* adv = type ? ad1 : ad0;
    unsigned short* Out = type ? O1 : O0;
    int wid = threadIdx.x >> 6;
    int lane = threadIdx.x & 63;
    int grp = lane >> 4;         // node within the wave's quad
    int cpos = lane & 15;        // channel block: channels cpos*8 .. cpos*8+7
    int node = (bid - (type ? gseg : 0)) * 16 + wid * 4 + grp;
    int start = rowptr[node];
    int deg = rowptr[node + 1] - start;
    float2 adn = *(const float2*)(adv + node * 2);

    // max deg across the wave's 4 groups (deg is uniform within a group)
    int md = max(deg, __shfl_xor(deg, 16, 64));
    md = max(md, __shfl_xor(md, 32, 64));

    float a[8] = {0.f, 0.f, 0.f, 0.f, 0.f, 0.f, 0.f, 0.f};
    float s0 = 0.f, s1 = 0.f;
    for (int i = 0; i < md; ++i) {
        if (i < deg) {
            int si = csr_src[start + i];                 // broadcast within group
            float2 av = *(const float2*)(asv + si * 2);  // broadcast within group
            float r0 = av.x + adn.x; r0 = r0 >= 0.f ? r0 : NEG * r0;
            float r1 = av.y + adn.y; r1 = r1 >= 0.f ? r1 : NEG * r1;
            float w0 = __expf(r0), w1 = __expf(r1);
            s0 += w0; s1 += w1;
            float wsel = cpos < 8 ? w0 : w1;
            uint4 rh = *(const uint4*)(Hfeat + (long)si * CDIM + cpos * 8);
            f16x8 h = __builtin_bit_cast(f16x8, rh);
#pragma unroll
            for (int k = 0; k < 8; ++k) a[k] = fmaf((float)h[k], wsel, a[k]);
        }
    }
    float ssel = cpos < 8 ? s0 : s1;
    float inv = ssel > 0.f ? 1.f / ssel : 0.f;
    uint4 o;
    o.x = (unsigned int)f2h(a[0] * inv) | ((unsigned int)f2h(a[1] * inv) << 16);
    o.y = (unsigned int)f2h(a[2] * inv) | ((unsigned int)f2h(a[3] * inv) << 16);
    o.z = (unsigned int)f2h(a[4] * inv) | ((unsigned int)f2h(a[5] * inv) << 16);
    o.w = (unsigned int)f2h(a[6] * inv) | ((unsigned int)f2h(a[7] * inv) << 16);
    *(uint4*)(Out + (long)node * CDIM + cpos * 8) = o;
}

// ---- final classifier with fused semantic combine (attn computed inline) ----
__global__ __launch_bounds__(256)
void final_linear_kernel(const unsigned short* __restrict__ O0,
                         const unsigned short* __restrict__ O1,
                         const float* __restrict__ saccp,
                         const float* __restrict__ lw, const float* __restrict__ lb,
                         float* __restrict__ out) {
    __shared__ float lws[CDIM * FOUT];
    int tid = threadIdx.x;
    for (int i = tid; i < CDIM * FOUT; i += 256) lws[i] = lw[i];
    __syncthreads();
    float fa0, fa1;
    attn_from_sacc(saccp, fa0, fa1);
    int idx = blockIdx.x * 256 + tid;
    if (idx >= NNODES * FOUT) return;
    int n = idx >> 3, o = idx & 7;
    const ushort8* r0 = (const ushort8*)(O0 + (long)n * CDIM);
    const ushort8* r1 = (const ushort8*)(O1 + (long)n * CDIM);
    float acc = lb[o];
#pragma unroll
    for (int k8 = 0; k8 < 16; ++k8) {
        ushort8 v0 = r0[k8];
        ushort8 v1 = r1[k8];
#pragma unroll
        for (int e = 0; e < 8; ++e) {
            float hv = fa0 * hrelu2f(v0[e]) + fa1 * hrelu2f(v1[e]);
            acc = fmaf(hv, lws[(k8 * 8 + e) * FOUT + o], acc);
        }
    }
    out[idx] = acc;
}

extern "C" void kernel_launch(void* const* d_in, const int* in_sizes, int n_in,
                              void* d_out, int out_size, void* d_ws, size_t ws_size,
                              hipStream_t stream) {
    const float* x          = (const float*)d_in[0];
    const int*   ei_spatial = (const int*)d_in[1];
    const int*   ei_similar = (const int*)d_in[2];
    const float* p1_proj_w  = (const float*)d_in[3];
    const float* p1_proj_b  = (const float*)d_in[4];
    const float* p1_att_src = (const float*)d_in[5];
    const float* p1_att_dst = (const float*)d_in[6];
    const float* p1_q       = (const float*)d_in[7];
    const float* p1_kw      = (const float*)d_in[8];
    const float* p1_kb      = (const float*)d_in[9];
    const float* p2_proj_w  = (const float*)d_in[10];
    const float* p2_proj_b  = (const float*)d_in[11];
    const float* p2_att_src = (const float*)d_in[12];
    const float* p2_att_dst = (const float*)d_in[13];
    const float* p2_q       = (const float*)d_in[14];
    const float* p2_kw      = (const float*)d_in[15];
    const float* p2_kb      = (const float*)d_in[16];
    const float* lin_w      = (const float*)d_in[17];
    const float* lin_b      = (const float*)d_in[18];

    float* ws = (float*)d_ws;
    const size_t nc = (size_t)NNODES * CDIM;
    const size_t nh2 = (size_t)NNODES * HHEADS;

    float* asrc = ws;                    // 2*N*H
    float* adst = asrc + 2 * nh2;        // 2*N*H
    float* sacc = adst + 2 * nh2;        // 4 (L1: [0..1], L2: [2..3])
    int* rowptr0 = (int*)(sacc + 4);     // N+1
    int* rowptr1 = rowptr0 + (NNODES + 1);
    int* cursor0 = rowptr1 + (NNODES + 1);  // N+1
    int* cursor1 = cursor0 + (NNODES + 1);
    int* cs0     = cursor1 + (NNODES + 1);  // E
    int* cs1     = cs0 + EEDGES;            // E
    int* deg0    = cs1 + EEDGES;            // N (deg0/deg1 contiguous for one memset)
    int* deg1    = deg0 + NNODES;           // N
    int* bsum0   = deg1 + NNODES;           // SB
    int* bsum1   = bsum0 + SB;              // SB
    uintptr_t kp = (uintptr_t)(bsum1 + SB);
    kp = (kp + 15) & ~(uintptr_t)15;
    unsigned short* p1T = (unsigned short*)kp;      // FIN*CDIM f16
    unsigned short* k1T = p1T + FIN * CDIM;         // CDIM*CDIM
    unsigned short* p2T = k1T + CDIM * CDIM;        // CDIM*CDIM
    unsigned short* k2T = p2T + CDIM * CDIM;        // CDIM*CDIM
    unsigned short* Hb  = k2T + CDIM * CDIM;        // N*C f16
    unsigned short* O0b = Hb + nc;
    unsigned short* O1b = O0b + nc;

    const int gE = (EEDGES + 255) / 256;
    const int gm = (NNODES + 63) / 64;      // 1563
    const int gseg = NNODES / 16;           // 6250 (exact)
    const int nh = NNODES * HHEADS;

    // ---- build CSR for both edge types (structure reused across layers) ----
    hipMemsetAsync(deg0, 0, 2 * NNODES * sizeof(int), stream);
    hist_dual<<<2 * gE, 256, 0, stream>>>(ei_spatial + EEDGES, deg0,
                                          ei_similar + EEDGES, deg1, gE);
    scan_partial_dual<<<2 * SB, 256, 0, stream>>>(deg0, bsum0, deg1, bsum1);
    scan_bsum_dual<<<1, 64, 0, stream>>>(bsum0, bsum1);
    scan_final_dual<<<2 * SB, 256, 0, stream>>>(deg0, bsum0, rowptr0, cursor0,
                                                deg1, bsum1, rowptr1, cursor1);
    fill_dual<<<2 * gE, 256, 0, stream>>>(ei_spatial, ei_spatial + EEDGES, cursor0, cs0,
                                          ei_similar, ei_similar + EEDGES, cursor1, cs1, gE);

    // ---- all weight transposes (both layers) + sacc zero, one dispatch ----
    const int cvtN = (FIN + 3 * CDIM) * CDIM;
    cvt_all<<<(cvtN + 255) / 256, 256, 0, stream>>>(
        p1_proj_w, p1_kw, p2_proj_w, p2_kw, p1T, k1T, p2T, k2T, sacc);

    // ================= Layer 1 =================
    proj_mfma<FIN, 0><<<gm, 256, 0, stream>>>(x, nullptr, nullptr, p1T, p1_proj_b,
                                              p1_att_src, p1_att_dst, Hb, asrc, adst);
    seg_aggregate_dual<<<2 * gseg, 256, 0, stream>>>(
        rowptr0, cs0, asrc, adst, O0b,
        rowptr1, cs1, asrc + nh, adst + nh, O1b, Hb, gseg);
    score_mfma_dual<<<2 * SNB, 256, 0, stream>>>(O0b, O1b, k1T, p1_kb, p1_q, sacc);

    // ================= Layer 2 (combine + attn-softmax fused into proj) =================
    proj_mfma<CDIM, 2><<<gm, 256, 0, stream>>>(O0b, O1b, sacc, p2T, p2_proj_b,
                                               p2_att_src, p2_att_dst, Hb, asrc, adst);
    seg_aggregate_dual<<<2 * gseg, 256, 0, stream>>>(
        rowptr0, cs0, asrc, adst, O0b,
        rowptr1, cs1, asrc + nh, adst + nh, O1b, Hb, gseg);
    score_mfma_dual<<<2 * SNB, 256, 0, stream>>>(O0b, O1b, k2T, p2_kb, p2_q, sacc + 2);

    // ================= Final classifier (combine + attn-softmax fused) =================
    const int gfin = (NNODES * FOUT + 255) / 256;
    final_linear_kernel<<<gfin, 256, 0, stream>>>(O0b, O1b, sacc + 2, lin_w, lin_b,
                                                  (float*)d_out);
}

// Round 18
// 475.275 us; speedup vs baseline: 1.0514x; 1.0035x over previous
//
#include <hip/hip_runtime.h>

#define NNODES 100000
#define EEDGES 600000
#define CDIM 128
#define HHEADS 2
#define DDIM 64
#define FIN 64
#define FOUT 8
#define NEG 0.2f

#define SB 200    // scan blocks
#define SCH 500   // nodes per scan block (200*500 = 100000 exactly)
#define SNB 384   // persistent score blocks per edge type
#define GEB 2344  // edge blocks per type ((E+255)/256)
#define CVB 448   // cvt blocks (ceil((FIN+3*CDIM)*CDIM/256))

typedef _Float16 f16x8 __attribute__((ext_vector_type(8)));
typedef unsigned short ushort8 __attribute__((ext_vector_type(8)));
typedef float f32x4 __attribute__((ext_vector_type(4)));

__device__ __forceinline__ float tanh_fast(float x) {
    float e = __expf(2.f * x);
    return 1.f - 2.f / (e + 1.f);
}

__device__ __forceinline__ unsigned short f2h(float x) {
    _Float16 h = (_Float16)x;                 // RNE
    return __builtin_bit_cast(unsigned short, h);
}
__device__ __forceinline__ float h2f(unsigned short u) {
    return (float)__builtin_bit_cast(_Float16, u);
}
__device__ __forceinline__ float hrelu2f(unsigned short u) {
    return (u & 0x8000) ? 0.f : (float)__builtin_bit_cast(_Float16, u);
}

// 2-way semantic softmax from raw score sums (recomputed inline by consumers)
__device__ __forceinline__ void attn_from_sacc(const float* saccp, float& fa0, float& fa1) {
    float s0 = saccp[0] / (float)NNODES;
    float s1 = saccp[1] / (float)NNODES;
    float m = fmaxf(s0, s1);
    float e0 = expf(s0 - m), e1 = expf(s1 - m);
    float inv = 1.f / (e0 + e1);
    fa0 = e0 * inv; fa1 = e1 * inv;
}

// ============ projection body (device fn): H = f16(X@W + b), fused attention dots ============
// MODE 0: X f32 (layer 1). MODE 2: X = a0*relu(O0)+a1*relu(O1), attn from sacc (layer 2).
template<int K, int MODE>
__device__ __forceinline__
void proj_body(const void* __restrict__ Xv, const void* __restrict__ Xv2,
               const float* __restrict__ saccp,
               const unsigned short* __restrict__ pwT_b,
               const float* __restrict__ bias,
               const float* __restrict__ att_src, const float* __restrict__ att_dst,
               unsigned short* __restrict__ Hout,
               float* __restrict__ a_src, float* __restrict__ a_dst, int pbid) {
    const int U = K / 8;
    __shared__ ushort8 smem[192 * (K / 8)];   // As8 [64][U] + Bs8 [128][U]
    ushort8* As8 = smem;
    ushort8* Bs8 = smem + 64 * U;
    int tid = threadIdx.x;
    int row0 = pbid * 64;
    float fa0 = 0.f, fa1 = 0.f;
    if (MODE == 2) attn_from_sacc(saccp, fa0, fa1);

#pragma unroll
    for (int i = 0; i < (64 * U) / 256; ++i) {
        int idx = tid + i * 256;
        int row = idx / U, u = idx % U;
        int grow = row0 + row;
        ushort8 v;
        if (grow < NNODES) {
            if (MODE == 2) {
                ushort8 v0 = ((const ushort8*)Xv)[(long)grow * U + u];
                ushort8 v1 = ((const ushort8*)Xv2)[(long)grow * U + u];
#pragma unroll
                for (int e = 0; e < 8; ++e)
                    v[e] = f2h(fa0 * hrelu2f(v0[e]) + fa1 * hrelu2f(v1[e]));
            } else {
                const float* p = (const float*)Xv + (long)grow * K + u * 8;
                float4 a = *(const float4*)p;
                float4 b = *(const float4*)(p + 4);
                v[0] = f2h(a.x); v[1] = f2h(a.y); v[2] = f2h(a.z); v[3] = f2h(a.w);
                v[4] = f2h(b.x); v[5] = f2h(b.y); v[6] = f2h(b.z); v[7] = f2h(b.w);
            }
        } else v = (ushort8)0;
        As8[row * U + (u ^ (row & 7))] = v;
    }
#pragma unroll
    for (int i = 0; i < (128 * U) / 256; ++i) {
        int idx = tid + i * 256;
        int c = idx / U, u = idx % U;
        Bs8[c * U + (u ^ (c & 7))] = ((const ushort8*)pwT_b)[idx];
    }
    __syncthreads();

    int l = tid & 63, w = tid >> 6;
    int lrow = w * 16 + (l & 15);
    int ug = l >> 4;
    f32x4 acc[8];
#pragma unroll
    for (int ct = 0; ct < 8; ++ct) acc[ct] = (f32x4)0.f;

#pragma unroll
    for (int kc = 0; kc < K / 32; ++kc) {
        int u = kc * 4 + ug;
        f16x8 af = __builtin_bit_cast(f16x8, As8[lrow * U + (u ^ (lrow & 7))]);
#pragma unroll
        for (int ct = 0; ct < 8; ++ct) {
            int c = ct * 16 + (l & 15);
            f16x8 bf = __builtin_bit_cast(f16x8, Bs8[c * U + (u ^ (c & 7))]);
            acc[ct] = __builtin_amdgcn_mfma_f32_16x16x32_f16(af, bf, acc[ct], 0, 0, 0);
        }
    }

    __syncthreads();
    unsigned short* Cs = (unsigned short*)smem;  // [64][128]
#pragma unroll
    for (int ct = 0; ct < 8; ++ct) {
        int c = ct * 16 + (l & 15);
        float bc = bias[c];
#pragma unroll
        for (int v = 0; v < 4; ++v) {
            int rr = w * 16 + (l >> 4) * 4 + v;
            Cs[rr * 128 + c] = f2h(acc[ct][v] + bc);
        }
    }
    __syncthreads();

    int r = tid >> 2, q = tid & 3;
    int grow = row0 + r;
    if (grow < NNODES) {
        float h[32];
        ushort8 hv[4];
#pragma unroll
        for (int j = 0; j < 4; ++j) {
            hv[j] = *(ushort8*)&Cs[r * 128 + q * 32 + j * 8];
#pragma unroll
            for (int e = 0; e < 8; ++e) h[j * 8 + e] = h2f(hv[j][e]);
        }
#pragma unroll
        for (int j = 0; j < 4; ++j)
            *(ushort8*)(Hout + (long)grow * CDIM + q * 32 + j * 8) = hv[j];
#pragma unroll
        for (int i = 0; i < 2; ++i) {
            float s = 0.f, d = 0.f;
#pragma unroll
            for (int j = 0; j < 32; ++j) {
                s = fmaf(h[j], att_src[i * CDIM + q * 32 + j], s);
                d = fmaf(h[j], att_dst[i * CDIM + q * 32 + j], d);
            }
            s += __shfl_xor(s, 1, 64);
            d += __shfl_xor(d, 1, 64);
            if ((q & 1) == 0) {
                int hh = q >> 1;
                long base = (long)i * NNODES * HHEADS + (long)grow * HHEADS + hh;
                a_src[base] = s;
                a_dst[base] = d;
            }
        }
    }
}

// ---- layer-1 mega kernel: CSR fill blocks (latency-bound) + proj blocks (compute) ----
__global__ __launch_bounds__(256)
void proj1_fill(const int* __restrict__ src0, const int* __restrict__ dst0,
                int* __restrict__ cur0, int* __restrict__ cs0,
                const int* __restrict__ src1, const int* __restrict__ dst1,
                int* __restrict__ cur1, int* __restrict__ cs1,
                const float* __restrict__ X,
                const unsigned short* __restrict__ pwT_b,
                const float* __restrict__ bias,
                const float* __restrict__ att_src, const float* __restrict__ att_dst,
                unsigned short* __restrict__ Hout,
                float* __restrict__ a_src, float* __restrict__ a_dst) {
    int bid = blockIdx.x;
    if (bid < 2 * GEB) {
        int type = bid >= GEB;
        const int* src = type ? src1 : src0;
        const int* dst = type ? dst1 : dst0;
        int* cursor = type ? cur1 : cur0;
        int* csr_src = type ? cs1 : cs0;
        int e = (bid - (type ? GEB : 0)) * 256 + threadIdx.x;
        if (e < EEDGES) {
            int pos = atomicAdd(&cursor[dst[e]], 1);
            csr_src[pos] = src[e];
        }
        return;
    }
    proj_body<FIN, 0>(X, nullptr, nullptr, pwT_b, bias, att_src, att_dst,
                      Hout, a_src, a_dst, bid - 2 * GEB);
}

// ---- layer-2 proj (combine fused) ----
__global__ __launch_bounds__(256)
void proj2_kernel(const void* __restrict__ Xv, const void* __restrict__ Xv2,
                  const float* __restrict__ saccp,
                  const unsigned short* __restrict__ pwT_b,
                  const float* __restrict__ bias,
                  const float* __restrict__ att_src, const float* __restrict__ att_dst,
                  unsigned short* __restrict__ Hout,
                  float* __restrict__ a_src, float* __restrict__ a_dst) {
    proj_body<CDIM, 2>(Xv, Xv2, saccp, pwT_b, bias, att_src, att_dst,
                       Hout, a_src, a_dst, blockIdx.x);
}

// ---- semantic score via MFMA (f16): persistent blocks, kw staged ONCE ----
__global__ __launch_bounds__(256, 3)
void score_mfma_dual(const unsigned short* __restrict__ O0b,
                     const unsigned short* __restrict__ O1b,
                     const unsigned short* __restrict__ kwT_b,
                     const float* __restrict__ kb, const float* __restrict__ q,
                     float* __restrict__ sacc) {
    __shared__ ushort8 As8[64 * 16];    // 16 KB
    __shared__ ushort8 Bs8[128 * 16];   // 32 KB
    __shared__ float red[4];
    const int NT = (NNODES + 63) / 64;  // 1563 row tiles
    int bid = blockIdx.x;
    int type = bid >= SNB;
    const unsigned short* Omb = type ? O1b : O0b;
    int bt = bid - (type ? SNB : 0);
    int tid = threadIdx.x;

#pragma unroll
    for (int i = 0; i < 8; ++i) {
        int idx = tid + i * 256;
        int c = idx >> 4, u = idx & 15;
        Bs8[c * 16 + (u ^ (c & 7))] = ((const ushort8*)kwT_b)[idx];
    }

    int l = tid & 63, w = tid >> 6;
    int lrow = w * 16 + (l & 15);
    int ug = l >> 4;
    float s = 0.f;

    ushort8 pre[4];
    {
        int row0 = bt * 64;
#pragma unroll
        for (int i = 0; i < 4; ++i) {
            int idx = tid + i * 256;
            int row = idx >> 4, u = idx & 15;
            int grow = row0 + row;
            ushort8 v = (ushort8)0;
            if (bt < NT && grow < NNODES) {
                v = ((const ushort8*)Omb)[(long)grow * 16 + u];
#pragma unroll
                for (int e = 0; e < 8; ++e) v[e] = (v[e] & 0x8000) ? 0 : v[e];  // f16 relu
            }
            pre[i] = v;
        }
    }

    for (int t = bt; t < NT; t += SNB) {
        __syncthreads();
#pragma unroll
        for (int i = 0; i < 4; ++i) {
            int idx = tid + i * 256;
            int row = idx >> 4, u = idx & 15;
            As8[row * 16 + (u ^ (row & 7))] = pre[i];
        }
        int tn = t + SNB;
        if (tn < NT) {
            int row0n = tn * 64;
#pragma unroll
            for (int i = 0; i < 4; ++i) {
                int idx = tid + i * 256;
                int row = idx >> 4, u = idx & 15;
                int grow = row0n + row;
                ushort8 v = (ushort8)0;
                if (grow < NNODES) {
                    v = ((const ushort8*)Omb)[(long)grow * 16 + u];
#pragma unroll
                    for (int e = 0; e < 8; ++e) v[e] = (v[e] & 0x8000) ? 0 : v[e];
                }
                pre[i] = v;
            }
        }
        __syncthreads();

        f32x4 acc[8];
#pragma unroll
        for (int ct = 0; ct < 8; ++ct) acc[ct] = (f32x4)0.f;
#pragma unroll
        for (int kc = 0; kc < 4; ++kc) {
            int u = kc * 4 + ug;
            f16x8 af = __builtin_bit_cast(f16x8, As8[lrow * 16 + (u ^ (lrow & 7))]);
#pragma unroll
            for (int ct = 0; ct < 8; ++ct) {
                int c = ct * 16 + (l & 15);
                f16x8 bf = __builtin_bit_cast(f16x8, Bs8[c * 16 + (u ^ (c & 7))]);
                acc[ct] = __builtin_amdgcn_mfma_f32_16x16x32_f16(af, bf, acc[ct], 0, 0, 0);
            }
        }
        int row0 = t * 64;
#pragma unroll
        for (int ct = 0; ct < 8; ++ct) {
            int c = ct * 16 + (l & 15);
            float qc = q[c], kbc = kb[c];
#pragma unroll
            for (int v = 0; v < 4; ++v) {
                int grow = row0 + w * 16 + (l >> 4) * 4 + v;
                if (grow < NNODES) s += qc * tanh_fast(acc[ct][v] + kbc);
            }
        }
    }

#pragma unroll
    for (int m = 32; m >= 1; m >>= 1) s += __shfl_xor(s, m, 64);
    if (l == 0) red[w] = s;
    __syncthreads();
    if (tid == 0) atomicAdd(sacc + type, red[0] + red[1] + red[2] + red[3]);
}

// ============ CSR build ============
// hist blocks (atomic latency) + weight cvt blocks (copy) in one launch; zeroes sacc.
__global__ __launch_bounds__(256)
void hist_cvt(const int* __restrict__ dst0, int* __restrict__ deg0,
              const int* __restrict__ dst1, int* __restrict__ deg1,
              const float* __restrict__ p1w, const float* __restrict__ k1w,
              const float* __restrict__ p2w, const float* __restrict__ k2w,
              unsigned short* __restrict__ p1T, unsigned short* __restrict__ k1T,
              unsigned short* __restrict__ p2T, unsigned short* __restrict__ k2T,
              float* __restrict__ sacc) {
    int bid = blockIdx.x;
    if (bid < 2 * GEB) {
        int type = bid >= GEB;
        const int* dst = type ? dst1 : dst0;
        int* deg = type ? deg1 : deg0;
        int e = (bid - (type ? GEB : 0)) * 256 + threadIdx.x;
        if (e < EEDGES) atomicAdd(&deg[dst[e]], 1);
        return;
    }
    int idx = (bid - 2 * GEB) * 256 + threadIdx.x;
    if (bid == 2 * GEB && threadIdx.x < 4) sacc[threadIdx.x] = 0.f;
    if (idx < FIN * CDIM) {                    // p1: [k][c] -> [c*FIN+k]
        int c = idx / FIN, k = idx % FIN;
        p1T[idx] = f2h(p1w[k * CDIM + c]);
    } else if (idx < (FIN + CDIM) * CDIM) {    // k1
        int j = idx - FIN * CDIM;
        int c = j >> 7, k = j & 127;
        k1T[j] = f2h(k1w[k * CDIM + c]);
    } else if (idx < (FIN + 2 * CDIM) * CDIM) { // p2
        int j = idx - (FIN + CDIM) * CDIM;
        int c = j >> 7, k = j & 127;
        p2T[j] = f2h(p2w[k * CDIM + c]);
    } else if (idx < (FIN + 3 * CDIM) * CDIM) { // k2
        int j = idx - (FIN + 2 * CDIM) * CDIM;
        int c = j >> 7, k = j & 127;
        k2T[j] = f2h(k2w[k * CDIM + c]);
    }
}

__global__ __launch_bounds__(256)
void scan_partial_dual(const int* __restrict__ deg0, int* __restrict__ bsum0,
                       const int* __restrict__ deg1, int* __restrict__ bsum1) {
    __shared__ int red[256];
    int bid = blockIdx.x;
    int type = bid >= SB;
    const int* deg = type ? deg1 : deg0;
    int* bsum = type ? bsum1 : bsum0;
    int b = bid - (type ? SB : 0), t = threadIdx.x;
    int s = 0;
    if (t < 250) {
        int base = b * SCH + t * 2;
        s = deg[base] + deg[base + 1];
    }
    red[t] = s;
    __syncthreads();
#pragma unroll
    for (int off = 128; off >= 1; off >>= 1) {
        if (t < off) red[t] += red[t + off];
        __syncthreads();
    }
    if (t == 0) bsum[b] = red[0];
}

__global__ void scan_bsum_dual(int* __restrict__ bsum0, int* __restrict__ bsum1) {
    int t = threadIdx.x;
    if (t < 2) {
        int* bsum = t ? bsum1 : bsum0;
        int run = 0;
        for (int i = 0; i < SB; ++i) { int v = bsum[i]; bsum[i] = run; run += v; }
    }
}

// writes rowptr AND cursor
__global__ __launch_bounds__(256)
void scan_final_dual(const int* __restrict__ deg0, const int* __restrict__ bsum0,
                     int* __restrict__ rowptr0, int* __restrict__ cursor0,
                     const int* __restrict__ deg1, const int* __restrict__ bsum1,
                     int* __restrict__ rowptr1, int* __restrict__ cursor1) {
    __shared__ int ts[256];
    int bid = blockIdx.x;
    int type = bid >= SB;
    const int* deg = type ? deg1 : deg0;
    const int* bsum = type ? bsum1 : bsum0;
    int* rowptr = type ? rowptr1 : rowptr0;
    int* cursor = type ? cursor1 : cursor0;
    int b = bid - (type ? SB : 0), t = threadIdx.x;
    int d0 = 0, d1 = 0;
    int base = b * SCH + t * 2;
    if (t < 250) { d0 = deg[base]; d1 = deg[base + 1]; }
    ts[t] = d0 + d1;
    __syncthreads();
#pragma unroll
    for (int off = 1; off < 256; off <<= 1) {
        int v = (t >= off) ? ts[t - off] : 0;
        __syncthreads();
        ts[t] += v;
        __syncthreads();
    }
    if (t < 250) {
        int excl = bsum[b] + (t > 0 ? ts[t - 1] : 0);
        rowptr[base] = excl;      cursor[base] = excl;
        rowptr[base + 1] = excl + d0;  cursor[base + 1] = excl + d0;
    }
    if (b == 0 && t == 0) rowptr[NNODES] = EEDGES;
}

// ============ single-pass aggregation v7: 16-lane group per node ============
__global__ __launch_bounds__(256)
void seg_aggregate_dual(const int* __restrict__ rp0, const int* __restrict__ cs0,
                        const float* __restrict__ as0, const float* __restrict__ ad0,
                        unsigned short* __restrict__ O0,
                        const int* __restrict__ rp1, const int* __restrict__ cs1,
                        const float* __restrict__ as1, const float* __restrict__ ad1,
                        unsigned short* __restrict__ O1,
                        const unsigned short* __restrict__ Hfeat, int gseg) {
    int bid = blockIdx.x;
    int type = bid >= gseg;
    const int* rowptr = type ? rp1 : rp0;
    const int* csr_src = type ? cs1 : cs0;
    const float* asv = type ? as1 : as0;
    const float* adv = type ? ad1 : ad0;
    unsigned short* Out = type ? O1 : O0;
    int wid = threadIdx.x >> 6;
    int lane = threadIdx.x & 63;
    int grp = lane >> 4;         // node within the wave's quad
    int cpos = lane & 15;        // channel block: channels cpos*8 .. cpos*8+7
    int node = (bid - (type ? gseg : 0)) * 16 + wid * 4 + grp;
    int start = rowptr[node];
    int deg = rowptr[node + 1] - start;
    float2 adn = *(const float2*)(adv + node * 2);

    int md = max(deg, __shfl_xor(deg, 16, 64));
    md = max(md, __shfl_xor(md, 32, 64));

    float a[8] = {0.f, 0.f, 0.f, 0.f, 0.f, 0.f, 0.f, 0.f};
    float s0 = 0.f, s1 = 0.f;
    for (int i = 0; i < md; ++i) {
        if (i < deg) {
            int si = csr_src[start + i];                 // broadcast within group
            float2 av = *(const float2*)(asv + si * 2);  // broadcast within group
            float r0 = av.x + adn.x; r0 = r0 >= 0.f ? r0 : NEG * r0;
            float r1 = av.y + adn.y; r1 = r1 >= 0.f ? r1 : NEG * r1;
            float w0 = __expf(r0), w1 = __expf(r1);
            s0 += w0; s1 += w1;
            float wsel = cpos < 8 ? w0 : w1;
            uint4 rh = *(const uint4*)(Hfeat + (long)si * CDIM + cpos * 8);
            f16x8 h = __builtin_bit_cast(f16x8, rh);
#pragma unroll
            for (int k = 0; k < 8; ++k) a[k] = fmaf((float)h[k], wsel, a[k]);
        }
    }
    float ssel = cpos < 8 ? s0 : s1;
    float inv = ssel > 0.f ? 1.f / ssel : 0.f;
    uint4 o;
    o.x = (unsigned int)f2h(a[0] * inv) | ((unsigned int)f2h(a[1] * inv) << 16);
    o.y = (unsigned int)f2h(a[2] * inv) | ((unsigned int)f2h(a[3] * inv) << 16);
    o.z = (unsigned int)f2h(a[4] * inv) | ((unsigned int)f2h(a[5] * inv) << 16);
    o.w = (unsigned int)f2h(a[6] * inv) | ((unsigned int)f2h(a[7] * inv) << 16);
    *(uint4*)(Out + (long)node * CDIM + cpos * 8) = o;
}

// ---- final classifier with fused semantic combine (attn computed inline) ----
__global__ __launch_bounds__(256)
void final_linear_kernel(const unsigned short* __restrict__ O0,
                         const unsigned short* __restrict__ O1,
                         const float* __restrict__ saccp,
                         const float* __restrict__ lw, const float* __restrict__ lb,
                         float* __restrict__ out) {
    __shared__ float lws[CDIM * FOUT];
    int tid = threadIdx.x;
    for (int i = tid; i < CDIM * FOUT; i += 256) lws[i] = lw[i];
    __syncthreads();
    float fa0, fa1;
    attn_from_sacc(saccp, fa0, fa1);
    int idx = blockIdx.x * 256 + tid;
    if (idx >= NNODES * FOUT) return;
    int n = idx >> 3, o = idx & 7;
    const ushort8* r0 = (const ushort8*)(O0 + (long)n * CDIM);
    const ushort8* r1 = (const ushort8*)(O1 + (long)n * CDIM);
    float acc = lb[o];
#pragma unroll
    for (int k8 = 0; k8 < 16; ++k8) {
        ushort8 v0 = r0[k8];
        ushort8 v1 = r1[k8];
#pragma unroll
        for (int e = 0; e < 8; ++e) {
            float hv = fa0 * hrelu2f(v0[e]) + fa1 * hrelu2f(v1[e]);
            acc = fmaf(hv, lws[(k8 * 8 + e) * FOUT + o], acc);
        }
    }
    out[idx] = acc;
}

extern "C" void kernel_launch(void* const* d_in, const int* in_sizes, int n_in,
                              void* d_out, int out_size, void* d_ws, size_t ws_size,
                              hipStream_t stream) {
    const float* x          = (const float*)d_in[0];
    const int*   ei_spatial = (const int*)d_in[1];
    const int*   ei_similar = (const int*)d_in[2];
    const float* p1_proj_w  = (const float*)d_in[3];
    const float* p1_proj_b  = (const float*)d_in[4];
    const float* p1_att_src = (const float*)d_in[5];
    const float* p1_att_dst = (const float*)d_in[6];
    const float* p1_q       = (const float*)d_in[7];
    const float* p1_kw      = (const float*)d_in[8];
    const float* p1_kb      = (const float*)d_in[9];
    const float* p2_proj_w  = (const float*)d_in[10];
    const float* p2_proj_b  = (const float*)d_in[11];
    const float* p2_att_src = (const float*)d_in[12];
    const float* p2_att_dst = (const float*)d_in[13];
    const float* p2_q       = (const float*)d_in[14];
    const float* p2_kw      = (const float*)d_in[15];
    const float* p2_kb      = (const float*)d_in[16];
    const float* lin_w      = (const float*)d_in[17];
    const float* lin_b      = (const float*)d_in[18];

    float* ws = (float*)d_ws;
    const size_t nc = (size_t)NNODES * CDIM;
    const size_t nh2 = (size_t)NNODES * HHEADS;

    float* asrc = ws;                    // 2*N*H
    float* adst = asrc + 2 * nh2;        // 2*N*H
    float* sacc = adst + 2 * nh2;        // 4 (L1: [0..1], L2: [2..3])
    int* rowptr0 = (int*)(sacc + 4);     // N+1
    int* rowptr1 = rowptr0 + (NNODES + 1);
    int* cursor0 = rowptr1 + (NNODES + 1);  // N+1
    int* cursor1 = cursor0 + (NNODES + 1);
    int* cs0     = cursor1 + (NNODES + 1);  // E
    int* cs1     = cs0 + EEDGES;            // E
    int* deg0    = cs1 + EEDGES;            // N (deg0/deg1 contiguous for one memset)
    int* deg1    = deg0 + NNODES;           // N
    int* bsum0   = deg1 + NNODES;           // SB
    int* bsum1   = bsum0 + SB;              // SB
    uintptr_t kp = (uintptr_t)(bsum1 + SB);
    kp = (kp + 15) & ~(uintptr_t)15;
    unsigned short* p1T = (unsigned short*)kp;      // FIN*CDIM f16
    unsigned short* k1T = p1T + FIN * CDIM;         // CDIM*CDIM
    unsigned short* p2T = k1T + CDIM * CDIM;        // CDIM*CDIM
    unsigned short* k2T = p2T + CDIM * CDIM;        // CDIM*CDIM
    unsigned short* Hb  = k2T + CDIM * CDIM;        // N*C f16
    unsigned short* O0b = Hb + nc;
    unsigned short* O1b = O0b + nc;

    const int gm = (NNODES + 63) / 64;      // 1563
    const int gseg = NNODES / 16;           // 6250 (exact)
    const int nh = NNODES * HHEADS;

    // ---- CSR build + weight cvt (hist & cvt overlapped in one launch) ----
    hipMemsetAsync(deg0, 0, 2 * NNODES * sizeof(int), stream);
    hist_cvt<<<2 * GEB + CVB, 256, 0, stream>>>(
        ei_spatial + EEDGES, deg0, ei_similar + EEDGES, deg1,
        p1_proj_w, p1_kw, p2_proj_w, p2_kw, p1T, k1T, p2T, k2T, sacc);
    scan_partial_dual<<<2 * SB, 256, 0, stream>>>(deg0, bsum0, deg1, bsum1);
    scan_bsum_dual<<<1, 64, 0, stream>>>(bsum0, bsum1);
    scan_final_dual<<<2 * SB, 256, 0, stream>>>(deg0, bsum0, rowptr0, cursor0,
                                                deg1, bsum1, rowptr1, cursor1);

    // ================= Layer 1 (CSR fill overlapped with proj compute) =================
    proj1_fill<<<2 * GEB + gm, 256, 0, stream>>>(
        ei_spatial, ei_spatial + EEDGES, cursor0, cs0,
        ei_similar, ei_similar + EEDGES, cursor1, cs1,
        x, p1T, p1_proj_b, p1_att_src, p1_att_dst, Hb, asrc, adst);
    seg_aggregate_dual<<<2 * gseg, 256, 0, stream>>>(
        rowptr0, cs0, asrc, adst, O0b,
        rowptr1, cs1, asrc + nh, adst + nh, O1b, Hb, gseg);
    score_mfma_dual<<<2 * SNB, 256, 0, stream>>>(O0b, O1b, k1T, p1_kb, p1_q, sacc);

    // ================= Layer 2 (combine + attn-softmax fused into proj) =================
    proj2_kernel<<<gm, 256, 0, stream>>>(O0b, O1b, sacc, p2T, p2_proj_b,
                                         p2_att_src, p2_att_dst, Hb, asrc, adst);
    seg_aggregate_dual<<<2 * gseg, 256, 0, stream>>>(
        rowptr0, cs0, asrc, adst, O0b,
        rowptr1, cs1, asrc + nh, adst + nh, O1b, Hb, gseg);
    score_mfma_dual<<<2 * SNB, 256, 0, stream>>>(O0b, O1b, k2T, p2_kb, p2_q, sacc + 2);

    // ================= Final classifier (combine + attn-softmax fused) =================
    const int gfin = (NNODES * FOUT + 255) / 256;
    final_linear_kernel<<<gfin, 256, 0, stream>>>(O0b, O1b, sacc + 2, lin_w, lin_b,
                                                  (float*)d_out);
}

// Round 19
// 410.985 us; speedup vs baseline: 1.2158x; 1.1564x over previous
//
#include <hip/hip_runtime.h>

#define NNODES 100000
#define EEDGES 600000
#define CDIM 128
#define HHEADS 2
#define DDIM 64
#define FIN 64
#define FOUT 8
#define NEG 0.2f

#define SB 200    // scan blocks
#define SCH 500   // nodes per scan block (200*500 = 100000 exactly)
#define SNB 384   // persistent score blocks per edge type
#define GEB 2344  // edge blocks per type ((E+255)/256)
#define CVB 448   // cvt blocks (ceil((FIN+3*CDIM)*CDIM/256))

typedef _Float16 f16x8 __attribute__((ext_vector_type(8)));
typedef unsigned short ushort8 __attribute__((ext_vector_type(8)));
typedef float f32x4 __attribute__((ext_vector_type(4)));

__device__ __forceinline__ float tanh_fast(float x) {
    float e = __expf(2.f * x);
    return 1.f - 2.f / (e + 1.f);
}

__device__ __forceinline__ unsigned short f2h(float x) {
    _Float16 h = (_Float16)x;                 // RNE
    return __builtin_bit_cast(unsigned short, h);
}
__device__ __forceinline__ float h2f(unsigned short u) {
    return (float)__builtin_bit_cast(_Float16, u);
}
__device__ __forceinline__ float hrelu2f(unsigned short u) {
    return (u & 0x8000) ? 0.f : (float)__builtin_bit_cast(_Float16, u);
}

// 2-way semantic softmax from raw score sums (recomputed inline by consumers)
__device__ __forceinline__ void attn_from_sacc(const float* saccp, float& fa0, float& fa1) {
    float s0 = saccp[0] / (float)NNODES;
    float s1 = saccp[1] / (float)NNODES;
    float m = fmaxf(s0, s1);
    float e0 = expf(s0 - m), e1 = expf(s1 - m);
    float inv = 1.f / (e0 + e1);
    fa0 = e0 * inv; fa1 = e1 * inv;
}

// ============ projection body (device fn): H = f16(X@W + b), fused attention dots ============
// MODE 0: X f32 (layer 1). MODE 2: X = a0*relu(O0)+a1*relu(O1), attn from sacc (layer 2).
template<int K, int MODE>
__device__ __forceinline__
void proj_body(const void* __restrict__ Xv, const void* __restrict__ Xv2,
               const float* __restrict__ saccp,
               const unsigned short* __restrict__ pwT_b,
               const float* __restrict__ bias,
               const float* __restrict__ att_src, const float* __restrict__ att_dst,
               unsigned short* __restrict__ Hout,
               float* __restrict__ a_src, float* __restrict__ a_dst, int pbid) {
    const int U = K / 8;
    __shared__ ushort8 smem[192 * (K / 8)];   // As8 [64][U] + Bs8 [128][U]
    ushort8* As8 = smem;
    ushort8* Bs8 = smem + 64 * U;
    int tid = threadIdx.x;
    int row0 = pbid * 64;
    float fa0 = 0.f, fa1 = 0.f;
    if (MODE == 2) attn_from_sacc(saccp, fa0, fa1);

#pragma unroll
    for (int i = 0; i < (64 * U) / 256; ++i) {
        int idx = tid + i * 256;
        int row = idx / U, u = idx % U;
        int grow = row0 + row;
        ushort8 v;
        if (grow < NNODES) {
            if (MODE == 2) {
                ushort8 v0 = ((const ushort8*)Xv)[(long)grow * U + u];
                ushort8 v1 = ((const ushort8*)Xv2)[(long)grow * U + u];
#pragma unroll
                for (int e = 0; e < 8; ++e)
                    v[e] = f2h(fa0 * hrelu2f(v0[e]) + fa1 * hrelu2f(v1[e]));
            } else {
                const float* p = (const float*)Xv + (long)grow * K + u * 8;
                float4 a = *(const float4*)p;
                float4 b = *(const float4*)(p + 4);
                v[0] = f2h(a.x); v[1] = f2h(a.y); v[2] = f2h(a.z); v[3] = f2h(a.w);
                v[4] = f2h(b.x); v[5] = f2h(b.y); v[6] = f2h(b.z); v[7] = f2h(b.w);
            }
        } else v = (ushort8)0;
        As8[row * U + (u ^ (row & 7))] = v;
    }
#pragma unroll
    for (int i = 0; i < (128 * U) / 256; ++i) {
        int idx = tid + i * 256;
        int c = idx / U, u = idx % U;
        Bs8[c * U + (u ^ (c & 7))] = ((const ushort8*)pwT_b)[idx];
    }
    __syncthreads();

    int l = tid & 63, w = tid >> 6;
    int lrow = w * 16 + (l & 15);
    int ug = l >> 4;
    f32x4 acc[8];
#pragma unroll
    for (int ct = 0; ct < 8; ++ct) acc[ct] = (f32x4)0.f;

#pragma unroll
    for (int kc = 0; kc < K / 32; ++kc) {
        int u = kc * 4 + ug;
        f16x8 af = __builtin_bit_cast(f16x8, As8[lrow * U + (u ^ (lrow & 7))]);
#pragma unroll
        for (int ct = 0; ct < 8; ++ct) {
            int c = ct * 16 + (l & 15);
            f16x8 bf = __builtin_bit_cast(f16x8, Bs8[c * U + (u ^ (c & 7))]);
            acc[ct] = __builtin_amdgcn_mfma_f32_16x16x32_f16(af, bf, acc[ct], 0, 0, 0);
        }
    }

    __syncthreads();
    unsigned short* Cs = (unsigned short*)smem;  // [64][128]
#pragma unroll
    for (int ct = 0; ct < 8; ++ct) {
        int c = ct * 16 + (l & 15);
        float bc = bias[c];
#pragma unroll
        for (int v = 0; v < 4; ++v) {
            int rr = w * 16 + (l >> 4) * 4 + v;
            Cs[rr * 128 + c] = f2h(acc[ct][v] + bc);
        }
    }
    __syncthreads();

    int r = tid >> 2, q = tid & 3;
    int grow = row0 + r;
    if (grow < NNODES) {
        float h[32];
        ushort8 hv[4];
#pragma unroll
        for (int j = 0; j < 4; ++j) {
            hv[j] = *(ushort8*)&Cs[r * 128 + q * 32 + j * 8];
#pragma unroll
            for (int e = 0; e < 8; ++e) h[j * 8 + e] = h2f(hv[j][e]);
        }
#pragma unroll
        for (int j = 0; j < 4; ++j)
            *(ushort8*)(Hout + (long)grow * CDIM + q * 32 + j * 8) = hv[j];
#pragma unroll
        for (int i = 0; i < 2; ++i) {
            float s = 0.f, d = 0.f;
#pragma unroll
            for (int j = 0; j < 32; ++j) {
                s = fmaf(h[j], att_src[i * CDIM + q * 32 + j], s);
                d = fmaf(h[j], att_dst[i * CDIM + q * 32 + j], d);
            }
            s += __shfl_xor(s, 1, 64);
            d += __shfl_xor(d, 1, 64);
            if ((q & 1) == 0) {
                int hh = q >> 1;
                long base = (long)i * NNODES * HHEADS + (long)grow * HHEADS + hh;
                a_src[base] = s;
                a_dst[base] = d;
            }
        }
    }
}

__global__ __launch_bounds__(256)
void proj1_kernel(const float* __restrict__ X,
                  const unsigned short* __restrict__ pwT_b,
                  const float* __restrict__ bias,
                  const float* __restrict__ att_src, const float* __restrict__ att_dst,
                  unsigned short* __restrict__ Hout,
                  float* __restrict__ a_src, float* __restrict__ a_dst) {
    proj_body<FIN, 0>(X, nullptr, nullptr, pwT_b, bias, att_src, att_dst,
                      Hout, a_src, a_dst, blockIdx.x);
}

__global__ __launch_bounds__(256)
void proj2_kernel(const void* __restrict__ Xv, const void* __restrict__ Xv2,
                  const float* __restrict__ saccp,
                  const unsigned short* __restrict__ pwT_b,
                  const float* __restrict__ bias,
                  const float* __restrict__ att_src, const float* __restrict__ att_dst,
                  unsigned short* __restrict__ Hout,
                  float* __restrict__ a_src, float* __restrict__ a_dst) {
    proj_body<CDIM, 2>(Xv, Xv2, saccp, pwT_b, bias, att_src, att_dst,
                       Hout, a_src, a_dst, blockIdx.x);
}

// ---- semantic score via MFMA (f16): persistent blocks, kw staged ONCE ----
__global__ __launch_bounds__(256, 3)
void score_mfma_dual(const unsigned short* __restrict__ O0b,
                     const unsigned short* __restrict__ O1b,
                     const unsigned short* __restrict__ kwT_b,
                     const float* __restrict__ kb, const float* __restrict__ q,
                     float* __restrict__ sacc) {
    __shared__ ushort8 As8[64 * 16];    // 16 KB
    __shared__ ushort8 Bs8[128 * 16];   // 32 KB
    __shared__ float red[4];
    const int NT = (NNODES + 63) / 64;  // 1563 row tiles
    int bid = blockIdx.x;
    int type = bid >= SNB;
    const unsigned short* Omb = type ? O1b : O0b;
    int bt = bid - (type ? SNB : 0);
    int tid = threadIdx.x;

#pragma unroll
    for (int i = 0; i < 8; ++i) {
        int idx = tid + i * 256;
        int c = idx >> 4, u = idx & 15;
        Bs8[c * 16 + (u ^ (c & 7))] = ((const ushort8*)kwT_b)[idx];
    }

    int l = tid & 63, w = tid >> 6;
    int lrow = w * 16 + (l & 15);
    int ug = l >> 4;
    float s = 0.f;

    ushort8 pre[4];
    {
        int row0 = bt * 64;
#pragma unroll
        for (int i = 0; i < 4; ++i) {
            int idx = tid + i * 256;
            int row = idx >> 4, u = idx & 15;
            int grow = row0 + row;
            ushort8 v = (ushort8)0;
            if (bt < NT && grow < NNODES) {
                v = ((const ushort8*)Omb)[(long)grow * 16 + u];
#pragma unroll
                for (int e = 0; e < 8; ++e) v[e] = (v[e] & 0x8000) ? 0 : v[e];  // f16 relu
            }
            pre[i] = v;
        }
    }

    for (int t = bt; t < NT; t += SNB) {
        __syncthreads();
#pragma unroll
        for (int i = 0; i < 4; ++i) {
            int idx = tid + i * 256;
            int row = idx >> 4, u = idx & 15;
            As8[row * 16 + (u ^ (row & 7))] = pre[i];
        }
        int tn = t + SNB;
        if (tn < NT) {
            int row0n = tn * 64;
#pragma unroll
            for (int i = 0; i < 4; ++i) {
                int idx = tid + i * 256;
                int row = idx >> 4, u = idx & 15;
                int grow = row0n + row;
                ushort8 v = (ushort8)0;
                if (grow < NNODES) {
                    v = ((const ushort8*)Omb)[(long)grow * 16 + u];
#pragma unroll
                    for (int e = 0; e < 8; ++e) v[e] = (v[e] & 0x8000) ? 0 : v[e];
                }
                pre[i] = v;
            }
        }
        __syncthreads();

        f32x4 acc[8];
#pragma unroll
        for (int ct = 0; ct < 8; ++ct) acc[ct] = (f32x4)0.f;
#pragma unroll
        for (int kc = 0; kc < 4; ++kc) {
            int u = kc * 4 + ug;
            f16x8 af = __builtin_bit_cast(f16x8, As8[lrow * 16 + (u ^ (lrow & 7))]);
#pragma unroll
            for (int ct = 0; ct < 8; ++ct) {
                int c = ct * 16 + (l & 15);
                f16x8 bf = __builtin_bit_cast(f16x8, Bs8[c * 16 + (u ^ (c & 7))]);
                acc[ct] = __builtin_amdgcn_mfma_f32_16x16x32_f16(af, bf, acc[ct], 0, 0, 0);
            }
        }
        int row0 = t * 64;
#pragma unroll
        for (int ct = 0; ct < 8; ++ct) {
            int c = ct * 16 + (l & 15);
            float qc = q[c], kbc = kb[c];
#pragma unroll
            for (int v = 0; v < 4; ++v) {
                int grow = row0 + w * 16 + (l >> 4) * 4 + v;
                if (grow < NNODES) s += qc * tanh_fast(acc[ct][v] + kbc);
            }
        }
    }

#pragma unroll
    for (int m = 32; m >= 1; m >>= 1) s += __shfl_xor(s, m, 64);
    if (l == 0) red[w] = s;
    __syncthreads();
    if (tid == 0) atomicAdd(sacc + type, red[0] + red[1] + red[2] + red[3]);
}

// ============ CSR build ============
// hist blocks (atomic latency; rank stored) + weight cvt blocks in one launch; zeroes sacc.
__global__ __launch_bounds__(256)
void hist_cvt(const int* __restrict__ dst0, int* __restrict__ deg0, int* __restrict__ rank0,
              const int* __restrict__ dst1, int* __restrict__ deg1, int* __restrict__ rank1,
              const float* __restrict__ p1w, const float* __restrict__ k1w,
              const float* __restrict__ p2w, const float* __restrict__ k2w,
              unsigned short* __restrict__ p1T, unsigned short* __restrict__ k1T,
              unsigned short* __restrict__ p2T, unsigned short* __restrict__ k2T,
              float* __restrict__ sacc) {
    int bid = blockIdx.x;
    if (bid < 2 * GEB) {
        int type = bid >= GEB;
        const int* dst = type ? dst1 : dst0;
        int* deg = type ? deg1 : deg0;
        int* rank = type ? rank1 : rank0;
        int e = (bid - (type ? GEB : 0)) * 256 + threadIdx.x;
        if (e < EEDGES) rank[e] = atomicAdd(&deg[dst[e]], 1);
        return;
    }
    int idx = (bid - 2 * GEB) * 256 + threadIdx.x;
    if (bid == 2 * GEB && threadIdx.x < 4) sacc[threadIdx.x] = 0.f;
    if (idx < FIN * CDIM) {                    // p1: [k][c] -> [c*FIN+k]
        int c = idx / FIN, k = idx % FIN;
        p1T[idx] = f2h(p1w[k * CDIM + c]);
    } else if (idx < (FIN + CDIM) * CDIM) {    // k1
        int j = idx - FIN * CDIM;
        int c = j >> 7, k = j & 127;
        k1T[j] = f2h(k1w[k * CDIM + c]);
    } else if (idx < (FIN + 2 * CDIM) * CDIM) { // p2
        int j = idx - (FIN + CDIM) * CDIM;
        int c = j >> 7, k = j & 127;
        p2T[j] = f2h(p2w[k * CDIM + c]);
    } else if (idx < (FIN + 3 * CDIM) * CDIM) { // k2
        int j = idx - (FIN + 2 * CDIM) * CDIM;
        int c = j >> 7, k = j & 127;
        k2T[j] = f2h(k2w[k * CDIM + c]);
    }
}

__global__ __launch_bounds__(256)
void scan_partial_dual(const int* __restrict__ deg0, int* __restrict__ bsum0,
                       const int* __restrict__ deg1, int* __restrict__ bsum1) {
    __shared__ int red[256];
    int bid = blockIdx.x;
    int type = bid >= SB;
    const int* deg = type ? deg1 : deg0;
    int* bsum = type ? bsum1 : bsum0;
    int b = bid - (type ? SB : 0), t = threadIdx.x;
    int s = 0;
    if (t < 250) {
        int base = b * SCH + t * 2;
        s = deg[base] + deg[base + 1];
    }
    red[t] = s;
    __syncthreads();
#pragma unroll
    for (int off = 128; off >= 1; off >>= 1) {
        if (t < off) red[t] += red[t + off];
        __syncthreads();
    }
    if (t == 0) bsum[b] = red[0];
}

__global__ void scan_bsum_dual(int* __restrict__ bsum0, int* __restrict__ bsum1) {
    int t = threadIdx.x;
    if (t < 2) {
        int* bsum = t ? bsum1 : bsum0;
        int run = 0;
        for (int i = 0; i < SB; ++i) { int v = bsum[i]; bsum[i] = run; run += v; }
    }
}

__global__ __launch_bounds__(256)
void scan_final_dual(const int* __restrict__ deg0, const int* __restrict__ bsum0,
                     int* __restrict__ rowptr0,
                     const int* __restrict__ deg1, const int* __restrict__ bsum1,
                     int* __restrict__ rowptr1) {
    __shared__ int ts[256];
    int bid = blockIdx.x;
    int type = bid >= SB;
    const int* deg = type ? deg1 : deg0;
    const int* bsum = type ? bsum1 : bsum0;
    int* rowptr = type ? rowptr1 : rowptr0;
    int b = bid - (type ? SB : 0), t = threadIdx.x;
    int d0 = 0, d1 = 0;
    int base = b * SCH + t * 2;
    if (t < 250) { d0 = deg[base]; d1 = deg[base + 1]; }
    ts[t] = d0 + d1;
    __syncthreads();
#pragma unroll
    for (int off = 1; off < 256; off <<= 1) {
        int v = (t >= off) ? ts[t - off] : 0;
        __syncthreads();
        ts[t] += v;
        __syncthreads();
    }
    if (t < 250) {
        int excl = bsum[b] + (t > 0 ? ts[t - 1] : 0);
        rowptr[base] = excl;
        rowptr[base + 1] = excl + d0;
    }
    if (b == 0 && t == 0) rowptr[NNODES] = EEDGES;
}

// atomic-free fill: pos = rowptr[dst] + rank (rank captured during hist)
__global__ __launch_bounds__(256)
void fill_dual(const int* __restrict__ src0, const int* __restrict__ dst0,
               const int* __restrict__ rank0, const int* __restrict__ rp0,
               int* __restrict__ cs0,
               const int* __restrict__ src1, const int* __restrict__ dst1,
               const int* __restrict__ rank1, const int* __restrict__ rp1,
               int* __restrict__ cs1) {
    int bid = blockIdx.x;
    int type = bid >= GEB;
    const int* src = type ? src1 : src0;
    const int* dst = type ? dst1 : dst0;
    const int* rank = type ? rank1 : rank0;
    const int* rowptr = type ? rp1 : rp0;
    int* csr_src = type ? cs1 : cs0;
    int e = (bid - (type ? GEB : 0)) * 256 + threadIdx.x;
    if (e < EEDGES) {
        int pos = rowptr[dst[e]] + rank[e];
        csr_src[pos] = src[e];
    }
}

// ============ single-pass aggregation v7: 16-lane group per node ============
__global__ __launch_bounds__(256)
void seg_aggregate_dual(const int* __restrict__ rp0, const int* __restrict__ cs0,
                        const float* __restrict__ as0, const float* __restrict__ ad0,
                        unsigned short* __restrict__ O0,
                        const int* __restrict__ rp1, const int* __restrict__ cs1,
                        const float* __restrict__ as1, const float* __restrict__ ad1,
                        unsigned short* __restrict__ O1,
                        const unsigned short* __restrict__ Hfeat, int gseg) {
    int bid = blockIdx.x;
    int type = bid >= gseg;
    const int* rowptr = type ? rp1 : rp0;
    const int* csr_src = type ? cs1 : cs0;
    const float* asv = type ? as1 : as0;
    const float* adv = type ? ad1 : ad0;
    unsigned short* Out = type ? O1 : O0;
    int wid = threadIdx.x >> 6;
    int lane = threadIdx.x & 63;
    int grp = lane >> 4;         // node within the wave's quad
    int cpos = lane & 15;        // channel block: channels cpos*8 .. cpos*8+7
    int node = (bid - (type ? gseg : 0)) * 16 + wid * 4 + grp;
    int start = rowptr[node];
    int deg = rowptr[node + 1] - start;
    float2 adn = *(const float2*)(adv + node * 2);

    int md = max(deg, __shfl_xor(deg, 16, 64));
    md = max(md, __shfl_xor(md, 32, 64));

    float a[8] = {0.f, 0.f, 0.f, 0.f, 0.f, 0.f, 0.f, 0.f};
    float s0 = 0.f, s1 = 0.f;
    for (int i = 0; i < md; ++i) {
        if (i < deg) {
            int si = csr_src[start + i];                 // broadcast within group
            float2 av = *(const float2*)(asv + si * 2);  // broadcast within group
            float r0 = av.x + adn.x; r0 = r0 >= 0.f ? r0 : NEG * r0;
            float r1 = av.y + adn.y; r1 = r1 >= 0.f ? r1 : NEG * r1;
            float w0 = __expf(r0), w1 = __expf(r1);
            s0 += w0; s1 += w1;
            float wsel = cpos < 8 ? w0 : w1;
            uint4 rh = *(const uint4*)(Hfeat + (long)si * CDIM + cpos * 8);
            f16x8 h = __builtin_bit_cast(f16x8, rh);
#pragma unroll
            for (int k = 0; k < 8; ++k) a[k] = fmaf((float)h[k], wsel, a[k]);
        }
    }
    float ssel = cpos < 8 ? s0 : s1;
    float inv = ssel > 0.f ? 1.f / ssel : 0.f;
    uint4 o;
    o.x = (unsigned int)f2h(a[0] * inv) | ((unsigned int)f2h(a[1] * inv) << 16);
    o.y = (unsigned int)f2h(a[2] * inv) | ((unsigned int)f2h(a[3] * inv) << 16);
    o.z = (unsigned int)f2h(a[4] * inv) | ((unsigned int)f2h(a[5] * inv) << 16);
    o.w = (unsigned int)f2h(a[6] * inv) | ((unsigned int)f2h(a[7] * inv) << 16);
    *(uint4*)(Out + (long)node * CDIM + cpos * 8) = o;
}

// ---- final classifier with fused semantic combine (attn computed inline) ----
__global__ __launch_bounds__(256)
void final_linear_kernel(const unsigned short* __restrict__ O0,
                         const unsigned short* __restrict__ O1,
                         const float* __restrict__ saccp,
                         const float* __restrict__ lw, const float* __restrict__ lb,
                         float* __restrict__ out) {
    __shared__ float lws[CDIM * FOUT];
    int tid = threadIdx.x;
    for (int i = tid; i < CDIM * FOUT; i += 256) lws[i] = lw[i];
    __syncthreads();
    float fa0, fa1;
    attn_from_sacc(saccp, fa0, fa1);
    int idx = blockIdx.x * 256 + tid;
    if (idx >= NNODES * FOUT) return;
    int n = idx >> 3, o = idx & 7;
    const ushort8* r0 = (const ushort8*)(O0 + (long)n * CDIM);
    const ushort8* r1 = (const ushort8*)(O1 + (long)n * CDIM);
    float acc = lb[o];
#pragma unroll
    for (int k8 = 0; k8 < 16; ++k8) {
        ushort8 v0 = r0[k8];
        ushort8 v1 = r1[k8];
#pragma unroll
        for (int e = 0; e < 8; ++e) {
            float hv = fa0 * hrelu2f(v0[e]) + fa1 * hrelu2f(v1[e]);
            acc = fmaf(hv, lws[(k8 * 8 + e) * FOUT + o], acc);
        }
    }
    out[idx] = acc;
}

extern "C" void kernel_launch(void* const* d_in, const int* in_sizes, int n_in,
                              void* d_out, int out_size, void* d_ws, size_t ws_size,
                              hipStream_t stream) {
    const float* x          = (const float*)d_in[0];
    const int*   ei_spatial = (const int*)d_in[1];
    const int*   ei_similar = (const int*)d_in[2];
    const float* p1_proj_w  = (const float*)d_in[3];
    const float* p1_proj_b  = (const float*)d_in[4];
    const float* p1_att_src = (const float*)d_in[5];
    const float* p1_att_dst = (const float*)d_in[6];
    const float* p1_q       = (const float*)d_in[7];
    const float* p1_kw      = (const float*)d_in[8];
    const float* p1_kb      = (const float*)d_in[9];
    const float* p2_proj_w  = (const float*)d_in[10];
    const float* p2_proj_b  = (const float*)d_in[11];
    const float* p2_att_src = (const float*)d_in[12];
    const float* p2_att_dst = (const float*)d_in[13];
    const float* p2_q       = (const float*)d_in[14];
    const float* p2_kw      = (const float*)d_in[15];
    const float* p2_kb      = (const float*)d_in[16];
    const float* lin_w      = (const float*)d_in[17];
    const float* lin_b      = (const float*)d_in[18];

    float* ws = (float*)d_ws;
    const size_t nc = (size_t)NNODES * CDIM;
    const size_t nh2 = (size_t)NNODES * HHEADS;

    float* asrc = ws;                    // 2*N*H
    float* adst = asrc + 2 * nh2;        // 2*N*H
    float* sacc = adst + 2 * nh2;        // 4 (L1: [0..1], L2: [2..3])
    int* rowptr0 = (int*)(sacc + 4);     // N+1
    int* rowptr1 = rowptr0 + (NNODES + 1);
    int* rank0   = rowptr1 + (NNODES + 1);  // E
    int* rank1   = rank0 + EEDGES;          // E
    int* cs0     = rank1 + EEDGES;          // E
    int* cs1     = cs0 + EEDGES;            // E
    int* deg0    = cs1 + EEDGES;            // N (deg0/deg1 contiguous for one memset)
    int* deg1    = deg0 + NNODES;           // N
    int* bsum0   = deg1 + NNODES;           // SB
    int* bsum1   = bsum0 + SB;              // SB
    uintptr_t kp = (uintptr_t)(bsum1 + SB);
    kp = (kp + 15) & ~(uintptr_t)15;
    unsigned short* p1T = (unsigned short*)kp;      // FIN*CDIM f16
    unsigned short* k1T = p1T + FIN * CDIM;         // CDIM*CDIM
    unsigned short* p2T = k1T + CDIM * CDIM;        // CDIM*CDIM
    unsigned short* k2T = p2T + CDIM * CDIM;        // CDIM*CDIM
    unsigned short* Hb  = k2T + CDIM * CDIM;        // N*C f16
    unsigned short* O0b = Hb + nc;
    unsigned short* O1b = O0b + nc;

    const int gm = (NNODES + 63) / 64;      // 1563
    const int gseg = NNODES / 16;           // 6250 (exact)
    const int nh = NNODES * HHEADS;

    // ---- CSR build + weight cvt (hist & cvt overlapped; rank captured) ----
    hipMemsetAsync(deg0, 0, 2 * NNODES * sizeof(int), stream);
    hist_cvt<<<2 * GEB + CVB, 256, 0, stream>>>(
        ei_spatial + EEDGES, deg0, rank0, ei_similar + EEDGES, deg1, rank1,
        p1_proj_w, p1_kw, p2_proj_w, p2_kw, p1T, k1T, p2T, k2T, sacc);
    scan_partial_dual<<<2 * SB, 256, 0, stream>>>(deg0, bsum0, deg1, bsum1);
    scan_bsum_dual<<<1, 64, 0, stream>>>(bsum0, bsum1);
    scan_final_dual<<<2 * SB, 256, 0, stream>>>(deg0, bsum0, rowptr0,
                                                deg1, bsum1, rowptr1);
    fill_dual<<<2 * GEB, 256, 0, stream>>>(
        ei_spatial, ei_spatial + EEDGES, rank0, rowptr0, cs0,
        ei_similar, ei_similar + EEDGES, rank1, rowptr1, cs1);

    // ================= Layer 1 =================
    proj1_kernel<<<gm, 256, 0, stream>>>(x, p1T, p1_proj_b, p1_att_src, p1_att_dst,
                                         Hb, asrc, adst);
    seg_aggregate_dual<<<2 * gseg, 256, 0, stream>>>(
        rowptr0, cs0, asrc, adst, O0b,
        rowptr1, cs1, asrc + nh, adst + nh, O1b, Hb, gseg);
    score_mfma_dual<<<2 * SNB, 256, 0, stream>>>(O0b, O1b, k1T, p1_kb, p1_q, sacc);

    // ================= Layer 2 (combine + attn-softmax fused into proj) =================
    proj2_kernel<<<gm, 256, 0, stream>>>(O0b, O1b, sacc, p2T, p2_proj_b,
                                         p2_att_src, p2_att_dst, Hb, asrc, adst);
    seg_aggregate_dual<<<2 * gseg, 256, 0, stream>>>(
        rowptr0, cs0, asrc, adst, O0b,
        rowptr1, cs1, asrc + nh, adst + nh, O1b, Hb, gseg);
    score_mfma_dual<<<2 * SNB, 256, 0, stream>>>(O0b, O1b, k2T, p2_kb, p2_q, sacc + 2);

    // ================= Final classifier (combine + attn-softmax fused) =================
    const int gfin = (NNODES * FOUT + 255) / 256;
    final_linear_kernel<<<gfin, 256, 0, stream>>>(O0b, O1b, sacc + 2, lin_w, lin_b,
                                                  (float*)d_out);
}

// Round 20
// 396.930 us; speedup vs baseline: 1.2589x; 1.0354x over previous
//
#include <hip/hip_runtime.h>

#define NNODES 100000
#define EEDGES 600000
#define CDIM 128
#define HHEADS 2
#define DDIM 64
#define FIN 64
#define FOUT 8
#define NEG 0.2f

#define SB 200    // scan blocks
#define SCH 500   // nodes per scan block (200*500 = 100000 exactly)
#define SNB 384   // persistent score blocks per edge type
#define GEB 2344  // edge blocks per type ((E+255)/256)
#define CVB 448   // cvt blocks (ceil((FIN+3*CDIM)*CDIM/256))

typedef _Float16 f16x8 __attribute__((ext_vector_type(8)));
typedef unsigned short ushort8 __attribute__((ext_vector_type(8)));
typedef float f32x4 __attribute__((ext_vector_type(4)));

__device__ __forceinline__ float tanh_fast(float x) {
    float e = __expf(2.f * x);
    return 1.f - 2.f / (e + 1.f);
}

__device__ __forceinline__ unsigned short f2h(float x) {
    _Float16 h = (_Float16)x;                 // RNE
    return __builtin_bit_cast(unsigned short, h);
}
__device__ __forceinline__ float h2f(unsigned short u) {
    return (float)__builtin_bit_cast(_Float16, u);
}
__device__ __forceinline__ float hrelu2f(unsigned short u) {
    return (u & 0x8000) ? 0.f : (float)__builtin_bit_cast(_Float16, u);
}

// 2-way semantic softmax from raw score sums (recomputed inline by consumers)
__device__ __forceinline__ void attn_from_sacc(const float* saccp, float& fa0, float& fa1) {
    float s0 = saccp[0] / (float)NNODES;
    float s1 = saccp[1] / (float)NNODES;
    float m = fmaxf(s0, s1);
    float e0 = expf(s0 - m), e1 = expf(s1 - m);
    float inv = 1.f / (e0 + e1);
    fa0 = e0 * inv; fa1 = e1 * inv;
}

// ============ projection body (device fn): H = f16(X@W + b), fused attention dots ============
template<int K, int MODE>
__device__ __forceinline__
void proj_body(const void* __restrict__ Xv, const void* __restrict__ Xv2,
               const float* __restrict__ saccp,
               const unsigned short* __restrict__ pwT_b,
               const float* __restrict__ bias,
               const float* __restrict__ att_src, const float* __restrict__ att_dst,
               unsigned short* __restrict__ Hout,
               float* __restrict__ a_src, float* __restrict__ a_dst, int pbid) {
    const int U = K / 8;
    __shared__ ushort8 smem[192 * (K / 8)];   // As8 [64][U] + Bs8 [128][U]
    ushort8* As8 = smem;
    ushort8* Bs8 = smem + 64 * U;
    int tid = threadIdx.x;
    int row0 = pbid * 64;
    float fa0 = 0.f, fa1 = 0.f;
    if (MODE == 2) attn_from_sacc(saccp, fa0, fa1);

#pragma unroll
    for (int i = 0; i < (64 * U) / 256; ++i) {
        int idx = tid + i * 256;
        int row = idx / U, u = idx % U;
        int grow = row0 + row;
        ushort8 v;
        if (grow < NNODES) {
            if (MODE == 2) {
                ushort8 v0 = ((const ushort8*)Xv)[(long)grow * U + u];
                ushort8 v1 = ((const ushort8*)Xv2)[(long)grow * U + u];
#pragma unroll
                for (int e = 0; e < 8; ++e)
                    v[e] = f2h(fa0 * hrelu2f(v0[e]) + fa1 * hrelu2f(v1[e]));
            } else {
                const float* p = (const float*)Xv + (long)grow * K + u * 8;
                float4 a = *(const float4*)p;
                float4 b = *(const float4*)(p + 4);
                v[0] = f2h(a.x); v[1] = f2h(a.y); v[2] = f2h(a.z); v[3] = f2h(a.w);
                v[4] = f2h(b.x); v[5] = f2h(b.y); v[6] = f2h(b.z); v[7] = f2h(b.w);
            }
        } else v = (ushort8)0;
        As8[row * U + (u ^ (row & 7))] = v;
    }
#pragma unroll
    for (int i = 0; i < (128 * U) / 256; ++i) {
        int idx = tid + i * 256;
        int c = idx / U, u = idx % U;
        Bs8[c * U + (u ^ (c & 7))] = ((const ushort8*)pwT_b)[idx];
    }
    __syncthreads();

    int l = tid & 63, w = tid >> 6;
    int lrow = w * 16 + (l & 15);
    int ug = l >> 4;
    f32x4 acc[8];
#pragma unroll
    for (int ct = 0; ct < 8; ++ct) acc[ct] = (f32x4)0.f;

#pragma unroll
    for (int kc = 0; kc < K / 32; ++kc) {
        int u = kc * 4 + ug;
        f16x8 af = __builtin_bit_cast(f16x8, As8[lrow * U + (u ^ (lrow & 7))]);
#pragma unroll
        for (int ct = 0; ct < 8; ++ct) {
            int c = ct * 16 + (l & 15);
            f16x8 bf = __builtin_bit_cast(f16x8, Bs8[c * U + (u ^ (c & 7))]);
            acc[ct] = __builtin_amdgcn_mfma_f32_16x16x32_f16(af, bf, acc[ct], 0, 0, 0);
        }
    }

    __syncthreads();
    unsigned short* Cs = (unsigned short*)smem;  // [64][128]
#pragma unroll
    for (int ct = 0; ct < 8; ++ct) {
        int c = ct * 16 + (l & 15);
        float bc = bias[c];
#pragma unroll
        for (int v = 0; v < 4; ++v) {
            int rr = w * 16 + (l >> 4) * 4 + v;
            Cs[rr * 128 + c] = f2h(acc[ct][v] + bc);
        }
    }
    __syncthreads();

    int r = tid >> 2, q = tid & 3;
    int grow = row0 + r;
    if (grow < NNODES) {
        float h[32];
        ushort8 hv[4];
#pragma unroll
        for (int j = 0; j < 4; ++j) {
            hv[j] = *(ushort8*)&Cs[r * 128 + q * 32 + j * 8];
#pragma unroll
            for (int e = 0; e < 8; ++e) h[j * 8 + e] = h2f(hv[j][e]);
        }
#pragma unroll
        for (int j = 0; j < 4; ++j)
            *(ushort8*)(Hout + (long)grow * CDIM + q * 32 + j * 8) = hv[j];
#pragma unroll
        for (int i = 0; i < 2; ++i) {
            float s = 0.f, d = 0.f;
#pragma unroll
            for (int j = 0; j < 32; ++j) {
                s = fmaf(h[j], att_src[i * CDIM + q * 32 + j], s);
                d = fmaf(h[j], att_dst[i * CDIM + q * 32 + j], d);
            }
            s += __shfl_xor(s, 1, 64);
            d += __shfl_xor(d, 1, 64);
            if ((q & 1) == 0) {
                int hh = q >> 1;
                long base = (long)i * NNODES * HHEADS + (long)grow * HHEADS + hh;
                a_src[base] = s;
                a_dst[base] = d;
            }
        }
    }
}

__global__ __launch_bounds__(256)
void proj1_kernel(const float* __restrict__ X,
                  const unsigned short* __restrict__ pwT_b,
                  const float* __restrict__ bias,
                  const float* __restrict__ att_src, const float* __restrict__ att_dst,
                  unsigned short* __restrict__ Hout,
                  float* __restrict__ a_src, float* __restrict__ a_dst) {
    proj_body<FIN, 0>(X, nullptr, nullptr, pwT_b, bias, att_src, att_dst,
                      Hout, a_src, a_dst, blockIdx.x);
}

__global__ __launch_bounds__(256)
void proj2_kernel(const void* __restrict__ Xv, const void* __restrict__ Xv2,
                  const float* __restrict__ saccp,
                  const unsigned short* __restrict__ pwT_b,
                  const float* __restrict__ bias,
                  const float* __restrict__ att_src, const float* __restrict__ att_dst,
                  unsigned short* __restrict__ Hout,
                  float* __restrict__ a_src, float* __restrict__ a_dst) {
    proj_body<CDIM, 2>(Xv, Xv2, saccp, pwT_b, bias, att_src, att_dst,
                       Hout, a_src, a_dst, blockIdx.x);
}

// ---- semantic score via MFMA (f16): persistent blocks, kw staged ONCE ----
__global__ __launch_bounds__(256, 3)
void score_mfma_dual(const unsigned short* __restrict__ O0b,
                     const unsigned short* __restrict__ O1b,
                     const unsigned short* __restrict__ kwT_b,
                     const float* __restrict__ kb, const float* __restrict__ q,
                     float* __restrict__ sacc) {
    __shared__ ushort8 As8[64 * 16];    // 16 KB
    __shared__ ushort8 Bs8[128 * 16];   // 32 KB
    __shared__ float red[4];
    const int NT = (NNODES + 63) / 64;  // 1563 row tiles
    int bid = blockIdx.x;
    int type = bid >= SNB;
    const unsigned short* Omb = type ? O1b : O0b;
    int bt = bid - (type ? SNB : 0);
    int tid = threadIdx.x;

#pragma unroll
    for (int i = 0; i < 8; ++i) {
        int idx = tid + i * 256;
        int c = idx >> 4, u = idx & 15;
        Bs8[c * 16 + (u ^ (c & 7))] = ((const ushort8*)kwT_b)[idx];
    }

    int l = tid & 63, w = tid >> 6;
    int lrow = w * 16 + (l & 15);
    int ug = l >> 4;
    float s = 0.f;

    ushort8 pre[4];
    {
        int row0 = bt * 64;
#pragma unroll
        for (int i = 0; i < 4; ++i) {
            int idx = tid + i * 256;
            int row = idx >> 4, u = idx & 15;
            int grow = row0 + row;
            ushort8 v = (ushort8)0;
            if (bt < NT && grow < NNODES) {
                v = ((const ushort8*)Omb)[(long)grow * 16 + u];
#pragma unroll
                for (int e = 0; e < 8; ++e) v[e] = (v[e] & 0x8000) ? 0 : v[e];  // f16 relu
            }
            pre[i] = v;
        }
    }

    for (int t = bt; t < NT; t += SNB) {
        __syncthreads();
#pragma unroll
        for (int i = 0; i < 4; ++i) {
            int idx = tid + i * 256;
            int row = idx >> 4, u = idx & 15;
            As8[row * 16 + (u ^ (row & 7))] = pre[i];
        }
        int tn = t + SNB;
        if (tn < NT) {
            int row0n = tn * 64;
#pragma unroll
            for (int i = 0; i < 4; ++i) {
                int idx = tid + i * 256;
                int row = idx >> 4, u = idx & 15;
                int grow = row0n + row;
                ushort8 v = (ushort8)0;
                if (grow < NNODES) {
                    v = ((const ushort8*)Omb)[(long)grow * 16 + u];
#pragma unroll
                    for (int e = 0; e < 8; ++e) v[e] = (v[e] & 0x8000) ? 0 : v[e];
                }
                pre[i] = v;
            }
        }
        __syncthreads();

        f32x4 acc[8];
#pragma unroll
        for (int ct = 0; ct < 8; ++ct) acc[ct] = (f32x4)0.f;
#pragma unroll
        for (int kc = 0; kc < 4; ++kc) {
            int u = kc * 4 + ug;
            f16x8 af = __builtin_bit_cast(f16x8, As8[lrow * 16 + (u ^ (lrow & 7))]);
#pragma unroll
            for (int ct = 0; ct < 8; ++ct) {
                int c = ct * 16 + (l & 15);
                f16x8 bf = __builtin_bit_cast(f16x8, Bs8[c * 16 + (u ^ (c & 7))]);
                acc[ct] = __builtin_amdgcn_mfma_f32_16x16x32_f16(af, bf, acc[ct], 0, 0, 0);
            }
        }
        int row0 = t * 64;
#pragma unroll
        for (int ct = 0; ct < 8; ++ct) {
            int c = ct * 16 + (l & 15);
            float qc = q[c], kbc = kb[c];
#pragma unroll
            for (int v = 0; v < 4; ++v) {
                int grow = row0 + w * 16 + (l >> 4) * 4 + v;
                if (grow < NNODES) s += qc * tanh_fast(acc[ct][v] + kbc);
            }
        }
    }

#pragma unroll
    for (int m = 32; m >= 1; m >>= 1) s += __shfl_xor(s, m, 64);
    if (l == 0) red[w] = s;
    __syncthreads();
    if (tid == 0) atomicAdd(sacc + type, red[0] + red[1] + red[2] + red[3]);
}

// ============ CSR build ============
__global__ __launch_bounds__(256)
void hist_cvt(const int* __restrict__ dst0, int* __restrict__ deg0, int* __restrict__ rank0,
              const int* __restrict__ dst1, int* __restrict__ deg1, int* __restrict__ rank1,
              const float* __restrict__ p1w, const float* __restrict__ k1w,
              const float* __restrict__ p2w, const float* __restrict__ k2w,
              unsigned short* __restrict__ p1T, unsigned short* __restrict__ k1T,
              unsigned short* __restrict__ p2T, unsigned short* __restrict__ k2T,
              float* __restrict__ sacc) {
    int bid = blockIdx.x;
    if (bid < 2 * GEB) {
        int type = bid >= GEB;
        const int* dst = type ? dst1 : dst0;
        int* deg = type ? deg1 : deg0;
        int* rank = type ? rank1 : rank0;
        int e = (bid - (type ? GEB : 0)) * 256 + threadIdx.x;
        if (e < EEDGES) rank[e] = atomicAdd(&deg[dst[e]], 1);
        return;
    }
    int idx = (bid - 2 * GEB) * 256 + threadIdx.x;
    if (bid == 2 * GEB && threadIdx.x < 4) sacc[threadIdx.x] = 0.f;
    if (idx < FIN * CDIM) {                    // p1: [k][c] -> [c*FIN+k]
        int c = idx / FIN, k = idx % FIN;
        p1T[idx] = f2h(p1w[k * CDIM + c]);
    } else if (idx < (FIN + CDIM) * CDIM) {    // k1
        int j = idx - FIN * CDIM;
        int c = j >> 7, k = j & 127;
        k1T[j] = f2h(k1w[k * CDIM + c]);
    } else if (idx < (FIN + 2 * CDIM) * CDIM) { // p2
        int j = idx - (FIN + CDIM) * CDIM;
        int c = j >> 7, k = j & 127;
        p2T[j] = f2h(p2w[k * CDIM + c]);
    } else if (idx < (FIN + 3 * CDIM) * CDIM) { // k2
        int j = idx - (FIN + 2 * CDIM) * CDIM;
        int c = j >> 7, k = j & 127;
        k2T[j] = f2h(k2w[k * CDIM + c]);
    }
}

__global__ __launch_bounds__(256)
void scan_partial_dual(const int* __restrict__ deg0, int* __restrict__ bsum0,
                       const int* __restrict__ deg1, int* __restrict__ bsum1) {
    __shared__ int red[256];
    int bid = blockIdx.x;
    int type = bid >= SB;
    const int* deg = type ? deg1 : deg0;
    int* bsum = type ? bsum1 : bsum0;
    int b = bid - (type ? SB : 0), t = threadIdx.x;
    int s = 0;
    if (t < 250) {
        int base = b * SCH + t * 2;
        s = deg[base] + deg[base + 1];
    }
    red[t] = s;
    __syncthreads();
#pragma unroll
    for (int off = 128; off >= 1; off >>= 1) {
        if (t < off) red[t] += red[t + off];
        __syncthreads();
    }
    if (t == 0) bsum[b] = red[0];
}

__global__ void scan_bsum_dual(int* __restrict__ bsum0, int* __restrict__ bsum1) {
    int t = threadIdx.x;
    if (t < 2) {
        int* bsum = t ? bsum1 : bsum0;
        int run = 0;
        for (int i = 0; i < SB; ++i) { int v = bsum[i]; bsum[i] = run; run += v; }
    }
}

__global__ __launch_bounds__(256)
void scan_final_dual(const int* __restrict__ deg0, const int* __restrict__ bsum0,
                     int* __restrict__ rowptr0,
                     const int* __restrict__ deg1, const int* __restrict__ bsum1,
                     int* __restrict__ rowptr1) {
    __shared__ int ts[256];
    int bid = blockIdx.x;
    int type = bid >= SB;
    const int* deg = type ? deg1 : deg0;
    const int* bsum = type ? bsum1 : bsum0;
    int* rowptr = type ? rowptr1 : rowptr0;
    int b = bid - (type ? SB : 0), t = threadIdx.x;
    int d0 = 0, d1 = 0;
    int base = b * SCH + t * 2;
    if (t < 250) { d0 = deg[base]; d1 = deg[base + 1]; }
    ts[t] = d0 + d1;
    __syncthreads();
#pragma unroll
    for (int off = 1; off < 256; off <<= 1) {
        int v = (t >= off) ? ts[t - off] : 0;
        __syncthreads();
        ts[t] += v;
        __syncthreads();
    }
    if (t < 250) {
        int excl = bsum[b] + (t > 0 ? ts[t - 1] : 0);
        rowptr[base] = excl;
        rowptr[base + 1] = excl + d0;
    }
    if (b == 0 && t == 0) rowptr[NNODES] = EEDGES;
}

// atomic-free fill: pos = rowptr[dst] + rank (rank captured during hist)
__global__ __launch_bounds__(256)
void fill_dual(const int* __restrict__ src0, const int* __restrict__ dst0,
               const int* __restrict__ rank0, const int* __restrict__ rp0,
               int* __restrict__ cs0,
               const int* __restrict__ src1, const int* __restrict__ dst1,
               const int* __restrict__ rank1, const int* __restrict__ rp1,
               int* __restrict__ cs1) {
    int bid = blockIdx.x;
    int type = bid >= GEB;
    const int* src = type ? src1 : src0;
    const int* dst = type ? dst1 : dst0;
    const int* rank = type ? rank1 : rank0;
    const int* rowptr = type ? rp1 : rp0;
    int* csr_src = type ? cs1 : cs0;
    int e = (bid - (type ? GEB : 0)) * 256 + threadIdx.x;
    if (e < EEDGES) {
        int pos = rowptr[dst[e]] + rank[e];
        csr_src[pos] = src[e];
    }
}

// ============ single-pass aggregation v8: 16-lane group per node, 2-edge unroll ======
// Wave = 4 nodes (16-lane groups); lane covers 8 f16 channels. Per iteration TWO edges'
// full load chains (csr x2, as x2, H x2) are issued back-to-back -> 2x memory-level
// parallelism. Divergent per-group loop bound handles inter-group deg variation via
// exec mask (replaces explicit md computation). 100000 = 6250*16 exactly.
__global__ __launch_bounds__(256)
void seg_aggregate_dual(const int* __restrict__ rp0, const int* __restrict__ cs0,
                        const float* __restrict__ as0, const float* __restrict__ ad0,
                        unsigned short* __restrict__ O0,
                        const int* __restrict__ rp1, const int* __restrict__ cs1,
                        const float* __restrict__ as1, const float* __restrict__ ad1,
                        unsigned short* __restrict__ O1,
                        const unsigned short* __restrict__ Hfeat, int gseg) {
    int bid = blockIdx.x;
    int type = bid >= gseg;
    const int* rowptr = type ? rp1 : rp0;
    const int* csr_src = type ? cs1 : cs0;
    const float* asv = type ? as1 : as0;
    const float* adv = type ? ad1 : ad0;
    unsigned short* Out = type ? O1 : O0;
    int wid = threadIdx.x >> 6;
    int lane = threadIdx.x & 63;
    int grp = lane >> 4;
    int cpos = lane & 15;        // channel block: channels cpos*8 .. cpos*8+7
    int node = (bid - (type ? gseg : 0)) * 16 + wid * 4 + grp;
    int start = rowptr[node];
    int deg = rowptr[node + 1] - start;
    float2 adn = *(const float2*)(adv + node * 2);

    float a[8] = {0.f, 0.f, 0.f, 0.f, 0.f, 0.f, 0.f, 0.f};
    float s0 = 0.f, s1 = 0.f;
    int i = 0;
    for (; i + 1 < deg; i += 2) {
        int siA = csr_src[start + i];
        int siB = csr_src[start + i + 1];
        float2 avA = *(const float2*)(asv + siA * 2);
        float2 avB = *(const float2*)(asv + siB * 2);
        uint4 rhA = *(const uint4*)(Hfeat + (long)siA * CDIM + cpos * 8);
        uint4 rhB = *(const uint4*)(Hfeat + (long)siB * CDIM + cpos * 8);
        float rA0 = avA.x + adn.x; rA0 = rA0 >= 0.f ? rA0 : NEG * rA0;
        float rA1 = avA.y + adn.y; rA1 = rA1 >= 0.f ? rA1 : NEG * rA1;
        float rB0 = avB.x + adn.x; rB0 = rB0 >= 0.f ? rB0 : NEG * rB0;
        float rB1 = avB.y + adn.y; rB1 = rB1 >= 0.f ? rB1 : NEG * rB1;
        float wA0 = __expf(rA0), wA1 = __expf(rA1);
        float wB0 = __expf(rB0), wB1 = __expf(rB1);
        s0 += wA0 + wB0; s1 += wA1 + wB1;
        float wA = cpos < 8 ? wA0 : wA1;
        float wB = cpos < 8 ? wB0 : wB1;
        f16x8 hA = __builtin_bit_cast(f16x8, rhA);
        f16x8 hB = __builtin_bit_cast(f16x8, rhB);
#pragma unroll
        for (int k = 0; k < 8; ++k) {
            a[k] = fmaf((float)hA[k], wA, a[k]);
            a[k] = fmaf((float)hB[k], wB, a[k]);
        }
    }
    if (i < deg) {
        int si = csr_src[start + i];
        float2 av = *(const float2*)(asv + si * 2);
        uint4 rh = *(const uint4*)(Hfeat + (long)si * CDIM + cpos * 8);
        float r0 = av.x + adn.x; r0 = r0 >= 0.f ? r0 : NEG * r0;
        float r1 = av.y + adn.y; r1 = r1 >= 0.f ? r1 : NEG * r1;
        float w0 = __expf(r0), w1 = __expf(r1);
        s0 += w0; s1 += w1;
        float wsel = cpos < 8 ? w0 : w1;
        f16x8 h = __builtin_bit_cast(f16x8, rh);
#pragma unroll
        for (int k = 0; k < 8; ++k) a[k] = fmaf((float)h[k], wsel, a[k]);
    }
    float ssel = cpos < 8 ? s0 : s1;
    float inv = ssel > 0.f ? 1.f / ssel : 0.f;
    uint4 o;
    o.x = (unsigned int)f2h(a[0] * inv) | ((unsigned int)f2h(a[1] * inv) << 16);
    o.y = (unsigned int)f2h(a[2] * inv) | ((unsigned int)f2h(a[3] * inv) << 16);
    o.z = (unsigned int)f2h(a[4] * inv) | ((unsigned int)f2h(a[5] * inv) << 16);
    o.w = (unsigned int)f2h(a[6] * inv) | ((unsigned int)f2h(a[7] * inv) << 16);
    *(uint4*)(Out + (long)node * CDIM + cpos * 8) = o;
}

// ---- final classifier with fused semantic combine (attn computed inline) ----
__global__ __launch_bounds__(256)
void final_linear_kernel(const unsigned short* __restrict__ O0,
                         const unsigned short* __restrict__ O1,
                         const float* __restrict__ saccp,
                         const float* __restrict__ lw, const float* __restrict__ lb,
                         float* __restrict__ out) {
    __shared__ float lws[CDIM * FOUT];
    int tid = threadIdx.x;
    for (int i = tid; i < CDIM * FOUT; i += 256) lws[i] = lw[i];
    __syncthreads();
    float fa0, fa1;
    attn_from_sacc(saccp, fa0, fa1);
    int idx = blockIdx.x * 256 + tid;
    if (idx >= NNODES * FOUT) return;
    int n = idx >> 3, o = idx & 7;
    const ushort8* r0 = (const ushort8*)(O0 + (long)n * CDIM);
    const ushort8* r1 = (const ushort8*)(O1 + (long)n * CDIM);
    float acc = lb[o];
#pragma unroll
    for (int k8 = 0; k8 < 16; ++k8) {
        ushort8 v0 = r0[k8];
        ushort8 v1 = r1[k8];
#pragma unroll
        for (int e = 0; e < 8; ++e) {
            float hv = fa0 * hrelu2f(v0[e]) + fa1 * hrelu2f(v1[e]);
            acc = fmaf(hv, lws[(k8 * 8 + e) * FOUT + o], acc);
        }
    }
    out[idx] = acc;
}

extern "C" void kernel_launch(void* const* d_in, const int* in_sizes, int n_in,
                              void* d_out, int out_size, void* d_ws, size_t ws_size,
                              hipStream_t stream) {
    const float* x          = (const float*)d_in[0];
    const int*   ei_spatial = (const int*)d_in[1];
    const int*   ei_similar = (const int*)d_in[2];
    const float* p1_proj_w  = (const float*)d_in[3];
    const float* p1_proj_b  = (const float*)d_in[4];
    const float* p1_att_src = (const float*)d_in[5];
    const float* p1_att_dst = (const float*)d_in[6];
    const float* p1_q       = (const float*)d_in[7];
    const float* p1_kw      = (const float*)d_in[8];
    const float* p1_kb      = (const float*)d_in[9];
    const float* p2_proj_w  = (const float*)d_in[10];
    const float* p2_proj_b  = (const float*)d_in[11];
    const float* p2_att_src = (const float*)d_in[12];
    const float* p2_att_dst = (const float*)d_in[13];
    const float* p2_q       = (const float*)d_in[14];
    const float* p2_kw      = (const float*)d_in[15];
    const float* p2_kb      = (const float*)d_in[16];
    const float* lin_w      = (const float*)d_in[17];
    const float* lin_b      = (const float*)d_in[18];

    float* ws = (float*)d_ws;
    const size_t nc = (size_t)NNODES * CDIM;
    const size_t nh2 = (size_t)NNODES * HHEADS;

    float* asrc = ws;                    // 2*N*H
    float* adst = asrc + 2 * nh2;        // 2*N*H
    float* sacc = adst + 2 * nh2;        // 4 (L1: [0..1], L2: [2..3])
    int* rowptr0 = (int*)(sacc + 4);     // N+1
    int* rowptr1 = rowptr0 + (NNODES + 1);
    int* rank0   = rowptr1 + (NNODES + 1);  // E
    int* rank1   = rank0 + EEDGES;          // E
    int* cs0     = rank1 + EEDGES;          // E
    int* cs1     = cs0 + EEDGES;            // E
    int* deg0    = cs1 + EEDGES;            // N (deg0/deg1 contiguous for one memset)
    int* deg1    = deg0 + NNODES;           // N
    int* bsum0   = deg1 + NNODES;           // SB
    int* bsum1   = bsum0 + SB;              // SB
    uintptr_t kp = (uintptr_t)(bsum1 + SB);
    kp = (kp + 15) & ~(uintptr_t)15;
    unsigned short* p1T = (unsigned short*)kp;      // FIN*CDIM f16
    unsigned short* k1T = p1T + FIN * CDIM;         // CDIM*CDIM
    unsigned short* p2T = k1T + CDIM * CDIM;        // CDIM*CDIM
    unsigned short* k2T = p2T + CDIM * CDIM;        // CDIM*CDIM
    unsigned short* Hb  = k2T + CDIM * CDIM;        // N*C f16
    unsigned short* O0b = Hb + nc;
    unsigned short* O1b = O0b + nc;

    const int gm = (NNODES + 63) / 64;      // 1563
    const int gseg = NNODES / 16;           // 6250 (exact)
    const int nh = NNODES * HHEADS;

    // ---- CSR build + weight cvt (hist & cvt overlapped; rank captured) ----
    hipMemsetAsync(deg0, 0, 2 * NNODES * sizeof(int), stream);
    hist_cvt<<<2 * GEB + CVB, 256, 0, stream>>>(
        ei_spatial + EEDGES, deg0, rank0, ei_similar + EEDGES, deg1, rank1,
        p1_proj_w, p1_kw, p2_proj_w, p2_kw, p1T, k1T, p2T, k2T, sacc);
    scan_partial_dual<<<2 * SB, 256, 0, stream>>>(deg0, bsum0, deg1, bsum1);
    scan_bsum_dual<<<1, 64, 0, stream>>>(bsum0, bsum1);
    scan_final_dual<<<2 * SB, 256, 0, stream>>>(deg0, bsum0, rowptr0,
                                                deg1, bsum1, rowptr1);
    fill_dual<<<2 * GEB, 256, 0, stream>>>(
        ei_spatial, ei_spatial + EEDGES, rank0, rowptr0, cs0,
        ei_similar, ei_similar + EEDGES, rank1, rowptr1, cs1);

    // ================= Layer 1 =================
    proj1_kernel<<<gm, 256, 0, stream>>>(x, p1T, p1_proj_b, p1_att_src, p1_att_dst,
                                         Hb, asrc, adst);
    seg_aggregate_dual<<<2 * gseg, 256, 0, stream>>>(
        rowptr0, cs0, asrc, adst, O0b,
        rowptr1, cs1, asrc + nh, adst + nh, O1b, Hb, gseg);
    score_mfma_dual<<<2 * SNB, 256, 0, stream>>>(O0b, O1b, k1T, p1_kb, p1_q, sacc);

    // ================= Layer 2 (combine + attn-softmax fused into proj) =================
    proj2_kernel<<<gm, 256, 0, stream>>>(O0b, O1b, sacc, p2T, p2_proj_b,
                                         p2_att_src, p2_att_dst, Hb, asrc, adst);
    seg_aggregate_dual<<<2 * gseg, 256, 0, stream>>>(
        rowptr0, cs0, asrc, adst, O0b,
        rowptr1, cs1, asrc + nh, adst + nh, O1b, Hb, gseg);
    score_mfma_dual<<<2 * SNB, 256, 0, stream>>>(O0b, O1b, k2T, p2_kb, p2_q, sacc + 2);

    // ================= Final classifier (combine + attn-softmax fused) =================
    const int gfin = (NNODES * FOUT + 255) / 256;
    final_linear_kernel<<<gfin, 256, 0, stream>>>(O0b, O1b, sacc + 2, lin_w, lin_b,
                                                  (float*)d_out);
}

// Round 21
// 395.980 us; speedup vs baseline: 1.2619x; 1.0024x over previous
//
#include <hip/hip_runtime.h>

#define NNODES 100000
#define EEDGES 600000
#define CDIM 128
#define HHEADS 2
#define DDIM 64
#define FIN 64
#define FOUT 8
#define NEG 0.2f

#define SB 200    // scan blocks
#define SCH 500   // nodes per scan block (200*500 = 100000 exactly)
#define SNB 384   // persistent score blocks per edge type
#define GEB 2344  // edge blocks per type ((E+255)/256)
#define CVB 448   // cvt blocks (ceil((FIN+3*CDIM)*CDIM/256))

typedef _Float16 f16x8 __attribute__((ext_vector_type(8)));
typedef unsigned short ushort8 __attribute__((ext_vector_type(8)));
typedef float f32x4 __attribute__((ext_vector_type(4)));

__device__ __forceinline__ float tanh_fast(float x) {
    float e = __expf(2.f * x);
    return 1.f - 2.f / (e + 1.f);
}

__device__ __forceinline__ unsigned short f2h(float x) {
    _Float16 h = (_Float16)x;                 // RNE
    return __builtin_bit_cast(unsigned short, h);
}
__device__ __forceinline__ float h2f(unsigned short u) {
    return (float)__builtin_bit_cast(_Float16, u);
}
__device__ __forceinline__ float hrelu2f(unsigned short u) {
    return (u & 0x8000) ? 0.f : (float)__builtin_bit_cast(_Float16, u);
}

// 2-way semantic softmax from raw score sums (recomputed inline by consumers)
__device__ __forceinline__ void attn_from_sacc(const float* saccp, float& fa0, float& fa1) {
    float s0 = saccp[0] / (float)NNODES;
    float s1 = saccp[1] / (float)NNODES;
    float m = fmaxf(s0, s1);
    float e0 = expf(s0 - m), e1 = expf(s1 - m);
    float inv = 1.f / (e0 + e1);
    fa0 = e0 * inv; fa1 = e1 * inv;
}

// ============ projection body (device fn): H = f16(X@W + b), fused attention dots ============
template<int K, int MODE>
__device__ __forceinline__
void proj_body(const void* __restrict__ Xv, const void* __restrict__ Xv2,
               const float* __restrict__ saccp,
               const unsigned short* __restrict__ pwT_b,
               const float* __restrict__ bias,
               const float* __restrict__ att_src, const float* __restrict__ att_dst,
               unsigned short* __restrict__ Hout,
               float* __restrict__ a_src, float* __restrict__ a_dst, int pbid) {
    const int U = K / 8;
    __shared__ ushort8 smem[192 * (K / 8)];   // As8 [64][U] + Bs8 [128][U]
    ushort8* As8 = smem;
    ushort8* Bs8 = smem + 64 * U;
    int tid = threadIdx.x;
    int row0 = pbid * 64;
    float fa0 = 0.f, fa1 = 0.f;
    if (MODE == 2) attn_from_sacc(saccp, fa0, fa1);

#pragma unroll
    for (int i = 0; i < (64 * U) / 256; ++i) {
        int idx = tid + i * 256;
        int row = idx / U, u = idx % U;
        int grow = row0 + row;
        ushort8 v;
        if (grow < NNODES) {
            if (MODE == 2) {
                ushort8 v0 = ((const ushort8*)Xv)[(long)grow * U + u];
                ushort8 v1 = ((const ushort8*)Xv2)[(long)grow * U + u];
#pragma unroll
                for (int e = 0; e < 8; ++e)
                    v[e] = f2h(fa0 * hrelu2f(v0[e]) + fa1 * hrelu2f(v1[e]));
            } else {
                const float* p = (const float*)Xv + (long)grow * K + u * 8;
                float4 a = *(const float4*)p;
                float4 b = *(const float4*)(p + 4);
                v[0] = f2h(a.x); v[1] = f2h(a.y); v[2] = f2h(a.z); v[3] = f2h(a.w);
                v[4] = f2h(b.x); v[5] = f2h(b.y); v[6] = f2h(b.z); v[7] = f2h(b.w);
            }
        } else v = (ushort8)0;
        As8[row * U + (u ^ (row & 7))] = v;
    }
#pragma unroll
    for (int i = 0; i < (128 * U) / 256; ++i) {
        int idx = tid + i * 256;
        int c = idx / U, u = idx % U;
        Bs8[c * U + (u ^ (c & 7))] = ((const ushort8*)pwT_b)[idx];
    }
    __syncthreads();

    int l = tid & 63, w = tid >> 6;
    int lrow = w * 16 + (l & 15);
    int ug = l >> 4;
    f32x4 acc[8];
#pragma unroll
    for (int ct = 0; ct < 8; ++ct) acc[ct] = (f32x4)0.f;

#pragma unroll
    for (int kc = 0; kc < K / 32; ++kc) {
        int u = kc * 4 + ug;
        f16x8 af = __builtin_bit_cast(f16x8, As8[lrow * U + (u ^ (lrow & 7))]);
#pragma unroll
        for (int ct = 0; ct < 8; ++ct) {
            int c = ct * 16 + (l & 15);
            f16x8 bf = __builtin_bit_cast(f16x8, Bs8[c * U + (u ^ (c & 7))]);
            acc[ct] = __builtin_amdgcn_mfma_f32_16x16x32_f16(af, bf, acc[ct], 0, 0, 0);
        }
    }

    __syncthreads();
    unsigned short* Cs = (unsigned short*)smem;  // [64][128]
#pragma unroll
    for (int ct = 0; ct < 8; ++ct) {
        int c = ct * 16 + (l & 15);
        float bc = bias[c];
#pragma unroll
        for (int v = 0; v < 4; ++v) {
            int rr = w * 16 + (l >> 4) * 4 + v;
            Cs[rr * 128 + c] = f2h(acc[ct][v] + bc);
        }
    }
    __syncthreads();

    int r = tid >> 2, q = tid & 3;
    int grow = row0 + r;
    if (grow < NNODES) {
        float h[32];
        ushort8 hv[4];
#pragma unroll
        for (int j = 0; j < 4; ++j) {
            hv[j] = *(ushort8*)&Cs[r * 128 + q * 32 + j * 8];
#pragma unroll
            for (int e = 0; e < 8; ++e) h[j * 8 + e] = h2f(hv[j][e]);
        }
#pragma unroll
        for (int j = 0; j < 4; ++j)
            *(ushort8*)(Hout + (long)grow * CDIM + q * 32 + j * 8) = hv[j];
#pragma unroll
        for (int i = 0; i < 2; ++i) {
            float s = 0.f, d = 0.f;
#pragma unroll
            for (int j = 0; j < 32; ++j) {
                s = fmaf(h[j], att_src[i * CDIM + q * 32 + j], s);
                d = fmaf(h[j], att_dst[i * CDIM + q * 32 + j], d);
            }
            s += __shfl_xor(s, 1, 64);
            d += __shfl_xor(d, 1, 64);
            if ((q & 1) == 0) {
                int hh = q >> 1;
                long base = (long)i * NNODES * HHEADS + (long)grow * HHEADS + hh;
                a_src[base] = s;
                a_dst[base] = d;
            }
        }
    }
}

__global__ __launch_bounds__(256)
void proj1_kernel(const float* __restrict__ X,
                  const unsigned short* __restrict__ pwT_b,
                  const float* __restrict__ bias,
                  const float* __restrict__ att_src, const float* __restrict__ att_dst,
                  unsigned short* __restrict__ Hout,
                  float* __restrict__ a_src, float* __restrict__ a_dst) {
    proj_body<FIN, 0>(X, nullptr, nullptr, pwT_b, bias, att_src, att_dst,
                      Hout, a_src, a_dst, blockIdx.x);
}

__global__ __launch_bounds__(256)
void proj2_kernel(const void* __restrict__ Xv, const void* __restrict__ Xv2,
                  const float* __restrict__ saccp,
                  const unsigned short* __restrict__ pwT_b,
                  const float* __restrict__ bias,
                  const float* __restrict__ att_src, const float* __restrict__ att_dst,
                  unsigned short* __restrict__ Hout,
                  float* __restrict__ a_src, float* __restrict__ a_dst) {
    proj_body<CDIM, 2>(Xv, Xv2, saccp, pwT_b, bias, att_src, att_dst,
                       Hout, a_src, a_dst, blockIdx.x);
}

// ---- semantic score via MFMA (f16): persistent blocks, kw staged ONCE ----
__global__ __launch_bounds__(256, 3)
void score_mfma_dual(const unsigned short* __restrict__ O0b,
                     const unsigned short* __restrict__ O1b,
                     const unsigned short* __restrict__ kwT_b,
                     const float* __restrict__ kb, const float* __restrict__ q,
                     float* __restrict__ sacc) {
    __shared__ ushort8 As8[64 * 16];    // 16 KB
    __shared__ ushort8 Bs8[128 * 16];   // 32 KB
    __shared__ float red[4];
    const int NT = (NNODES + 63) / 64;  // 1563 row tiles
    int bid = blockIdx.x;
    int type = bid >= SNB;
    const unsigned short* Omb = type ? O1b : O0b;
    int bt = bid - (type ? SNB : 0);
    int tid = threadIdx.x;

#pragma unroll
    for (int i = 0; i < 8; ++i) {
        int idx = tid + i * 256;
        int c = idx >> 4, u = idx & 15;
        Bs8[c * 16 + (u ^ (c & 7))] = ((const ushort8*)kwT_b)[idx];
    }

    int l = tid & 63, w = tid >> 6;
    int lrow = w * 16 + (l & 15);
    int ug = l >> 4;
    float s = 0.f;

    ushort8 pre[4];
    {
        int row0 = bt * 64;
#pragma unroll
        for (int i = 0; i < 4; ++i) {
            int idx = tid + i * 256;
            int row = idx >> 4, u = idx & 15;
            int grow = row0 + row;
            ushort8 v = (ushort8)0;
            if (bt < NT && grow < NNODES) {
                v = ((const ushort8*)Omb)[(long)grow * 16 + u];
#pragma unroll
                for (int e = 0; e < 8; ++e) v[e] = (v[e] & 0x8000) ? 0 : v[e];  // f16 relu
            }
            pre[i] = v;
        }
    }

    for (int t = bt; t < NT; t += SNB) {
        __syncthreads();
#pragma unroll
        for (int i = 0; i < 4; ++i) {
            int idx = tid + i * 256;
            int row = idx >> 4, u = idx & 15;
            As8[row * 16 + (u ^ (row & 7))] = pre[i];
        }
        int tn = t + SNB;
        if (tn < NT) {
            int row0n = tn * 64;
#pragma unroll
            for (int i = 0; i < 4; ++i) {
                int idx = tid + i * 256;
                int row = idx >> 4, u = idx & 15;
                int grow = row0n + row;
                ushort8 v = (ushort8)0;
                if (grow < NNODES) {
                    v = ((const ushort8*)Omb)[(long)grow * 16 + u];
#pragma unroll
                    for (int e = 0; e < 8; ++e) v[e] = (v[e] & 0x8000) ? 0 : v[e];
                }
                pre[i] = v;
            }
        }
        __syncthreads();

        f32x4 acc[8];
#pragma unroll
        for (int ct = 0; ct < 8; ++ct) acc[ct] = (f32x4)0.f;
#pragma unroll
        for (int kc = 0; kc < 4; ++kc) {
            int u = kc * 4 + ug;
            f16x8 af = __builtin_bit_cast(f16x8, As8[lrow * 16 + (u ^ (lrow & 7))]);
#pragma unroll
            for (int ct = 0; ct < 8; ++ct) {
                int c = ct * 16 + (l & 15);
                f16x8 bf = __builtin_bit_cast(f16x8, Bs8[c * 16 + (u ^ (c & 7))]);
                acc[ct] = __builtin_amdgcn_mfma_f32_16x16x32_f16(af, bf, acc[ct], 0, 0, 0);
            }
        }
        int row0 = t * 64;
#pragma unroll
        for (int ct = 0; ct < 8; ++ct) {
            int c = ct * 16 + (l & 15);
            float qc = q[c], kbc = kb[c];
#pragma unroll
            for (int v = 0; v < 4; ++v) {
                int grow = row0 + w * 16 + (l >> 4) * 4 + v;
                if (grow < NNODES) s += qc * tanh_fast(acc[ct][v] + kbc);
            }
        }
    }

#pragma unroll
    for (int m = 32; m >= 1; m >>= 1) s += __shfl_xor(s, m, 64);
    if (l == 0) red[w] = s;
    __syncthreads();
    if (tid == 0) atomicAdd(sacc + type, red[0] + red[1] + red[2] + red[3]);
}

// ============ CSR build ============
__global__ __launch_bounds__(256)
void hist_cvt(const int* __restrict__ dst0, int* __restrict__ deg0, int* __restrict__ rank0,
              const int* __restrict__ dst1, int* __restrict__ deg1, int* __restrict__ rank1,
              const float* __restrict__ p1w, const float* __restrict__ k1w,
              const float* __restrict__ p2w, const float* __restrict__ k2w,
              unsigned short* __restrict__ p1T, unsigned short* __restrict__ k1T,
              unsigned short* __restrict__ p2T, unsigned short* __restrict__ k2T,
              float* __restrict__ sacc) {
    int bid = blockIdx.x;
    if (bid < 2 * GEB) {
        int type = bid >= GEB;
        const int* dst = type ? dst1 : dst0;
        int* deg = type ? deg1 : deg0;
        int* rank = type ? rank1 : rank0;
        int e = (bid - (type ? GEB : 0)) * 256 + threadIdx.x;
        if (e < EEDGES) rank[e] = atomicAdd(&deg[dst[e]], 1);
        return;
    }
    int idx = (bid - 2 * GEB) * 256 + threadIdx.x;
    if (bid == 2 * GEB && threadIdx.x < 4) sacc[threadIdx.x] = 0.f;
    if (idx < FIN * CDIM) {                    // p1: [k][c] -> [c*FIN+k]
        int c = idx / FIN, k = idx % FIN;
        p1T[idx] = f2h(p1w[k * CDIM + c]);
    } else if (idx < (FIN + CDIM) * CDIM) {    // k1
        int j = idx - FIN * CDIM;
        int c = j >> 7, k = j & 127;
        k1T[j] = f2h(k1w[k * CDIM + c]);
    } else if (idx < (FIN + 2 * CDIM) * CDIM) { // p2
        int j = idx - (FIN + CDIM) * CDIM;
        int c = j >> 7, k = j & 127;
        p2T[j] = f2h(p2w[k * CDIM + c]);
    } else if (idx < (FIN + 3 * CDIM) * CDIM) { // k2
        int j = idx - (FIN + 2 * CDIM) * CDIM;
        int c = j >> 7, k = j & 127;
        k2T[j] = f2h(k2w[k * CDIM + c]);
    }
}

__global__ __launch_bounds__(256)
void scan_partial_dual(const int* __restrict__ deg0, int* __restrict__ bsum0,
                       const int* __restrict__ deg1, int* __restrict__ bsum1) {
    __shared__ int red[256];
    int bid = blockIdx.x;
    int type = bid >= SB;
    const int* deg = type ? deg1 : deg0;
    int* bsum = type ? bsum1 : bsum0;
    int b = bid - (type ? SB : 0), t = threadIdx.x;
    int s = 0;
    if (t < 250) {
        int base = b * SCH + t * 2;
        s = deg[base] + deg[base + 1];
    }
    red[t] = s;
    __syncthreads();
#pragma unroll
    for (int off = 128; off >= 1; off >>= 1) {
        if (t < off) red[t] += red[t + off];
        __syncthreads();
    }
    if (t == 0) bsum[b] = red[0];
}

__global__ void scan_bsum_dual(int* __restrict__ bsum0, int* __restrict__ bsum1) {
    int t = threadIdx.x;
    if (t < 2) {
        int* bsum = t ? bsum1 : bsum0;
        int run = 0;
        for (int i = 0; i < SB; ++i) { int v = bsum[i]; bsum[i] = run; run += v; }
    }
}

__global__ __launch_bounds__(256)
void scan_final_dual(const int* __restrict__ deg0, const int* __restrict__ bsum0,
                     int* __restrict__ rowptr0,
                     const int* __restrict__ deg1, const int* __restrict__ bsum1,
                     int* __restrict__ rowptr1) {
    __shared__ int ts[256];
    int bid = blockIdx.x;
    int type = bid >= SB;
    const int* deg = type ? deg1 : deg0;
    const int* bsum = type ? bsum1 : bsum0;
    int* rowptr = type ? rowptr1 : rowptr0;
    int b = bid - (type ? SB : 0), t = threadIdx.x;
    int d0 = 0, d1 = 0;
    int base = b * SCH + t * 2;
    if (t < 250) { d0 = deg[base]; d1 = deg[base + 1]; }
    ts[t] = d0 + d1;
    __syncthreads();
#pragma unroll
    for (int off = 1; off < 256; off <<= 1) {
        int v = (t >= off) ? ts[t - off] : 0;
        __syncthreads();
        ts[t] += v;
        __syncthreads();
    }
    if (t < 250) {
        int excl = bsum[b] + (t > 0 ? ts[t - 1] : 0);
        rowptr[base] = excl;
        rowptr[base + 1] = excl + d0;
    }
    if (b == 0 && t == 0) rowptr[NNODES] = EEDGES;
}

// atomic-free fill: pos = rowptr[dst] + rank (rank captured during hist)
__global__ __launch_bounds__(256)
void fill_dual(const int* __restrict__ src0, const int* __restrict__ dst0,
               const int* __restrict__ rank0, const int* __restrict__ rp0,
               int* __restrict__ cs0,
               const int* __restrict__ src1, const int* __restrict__ dst1,
               const int* __restrict__ rank1, const int* __restrict__ rp1,
               int* __restrict__ cs1) {
    int bid = blockIdx.x;
    int type = bid >= GEB;
    const int* src = type ? src1 : src0;
    const int* dst = type ? dst1 : dst0;
    const int* rank = type ? rank1 : rank0;
    const int* rowptr = type ? rp1 : rp0;
    int* csr_src = type ? cs1 : cs0;
    int e = (bid - (type ? GEB : 0)) * 256 + threadIdx.x;
    if (e < EEDGES) {
        int pos = rowptr[dst[e]] + rank[e];
        csr_src[pos] = src[e];
    }
}

// ============ single-pass aggregation v9: 16-lane group per node, 4-edge unroll ======
// Wave = 4 nodes (16-lane groups); lane covers 8 f16 channels. Per iteration FOUR edges'
// full load chains issued back-to-back -> 4x memory-level parallelism per group.
// 4+2+1 tail cascade. 100000 = 6250*16 exactly.
__global__ __launch_bounds__(256)
void seg_aggregate_dual(const int* __restrict__ rp0, const int* __restrict__ cs0,
                        const float* __restrict__ as0, const float* __restrict__ ad0,
                        unsigned short* __restrict__ O0,
                        const int* __restrict__ rp1, const int* __restrict__ cs1,
                        const float* __restrict__ as1, const float* __restrict__ ad1,
                        unsigned short* __restrict__ O1,
                        const unsigned short* __restrict__ Hfeat, int gseg) {
    int bid = blockIdx.x;
    int type = bid >= gseg;
    const int* rowptr = type ? rp1 : rp0;
    const int* csr_src = type ? cs1 : cs0;
    const float* asv = type ? as1 : as0;
    const float* adv = type ? ad1 : ad0;
    unsigned short* Out = type ? O1 : O0;
    int wid = threadIdx.x >> 6;
    int lane = threadIdx.x & 63;
    int grp = lane >> 4;
    int cpos = lane & 15;        // channel block: channels cpos*8 .. cpos*8+7
    int node = (bid - (type ? gseg : 0)) * 16 + wid * 4 + grp;
    int start = rowptr[node];
    int deg = rowptr[node + 1] - start;
    float2 adn = *(const float2*)(adv + node * 2);
    const unsigned short* __restrict__ Hc = Hfeat + cpos * 8;

    float a[8] = {0.f, 0.f, 0.f, 0.f, 0.f, 0.f, 0.f, 0.f};
    float s0 = 0.f, s1 = 0.f;
    int i = 0;
    for (; i + 3 < deg; i += 4) {
        int siA = csr_src[start + i];
        int siB = csr_src[start + i + 1];
        int siC = csr_src[start + i + 2];
        int siD = csr_src[start + i + 3];
        float2 avA = *(const float2*)(asv + siA * 2);
        float2 avB = *(const float2*)(asv + siB * 2);
        float2 avC = *(const float2*)(asv + siC * 2);
        float2 avD = *(const float2*)(asv + siD * 2);
        uint4 rhA = *(const uint4*)(Hc + (long)siA * CDIM);
        uint4 rhB = *(const uint4*)(Hc + (long)siB * CDIM);
        uint4 rhC = *(const uint4*)(Hc + (long)siC * CDIM);
        uint4 rhD = *(const uint4*)(Hc + (long)siD * CDIM);
        float rA0 = avA.x + adn.x; rA0 = rA0 >= 0.f ? rA0 : NEG * rA0;
        float rA1 = avA.y + adn.y; rA1 = rA1 >= 0.f ? rA1 : NEG * rA1;
        float rB0 = avB.x + adn.x; rB0 = rB0 >= 0.f ? rB0 : NEG * rB0;
        float rB1 = avB.y + adn.y; rB1 = rB1 >= 0.f ? rB1 : NEG * rB1;
        float rC0 = avC.x + adn.x; rC0 = rC0 >= 0.f ? rC0 : NEG * rC0;
        float rC1 = avC.y + adn.y; rC1 = rC1 >= 0.f ? rC1 : NEG * rC1;
        float rD0 = avD.x + adn.x; rD0 = rD0 >= 0.f ? rD0 : NEG * rD0;
        float rD1 = avD.y + adn.y; rD1 = rD1 >= 0.f ? rD1 : NEG * rD1;
        float wA0 = __expf(rA0), wA1 = __expf(rA1);
        float wB0 = __expf(rB0), wB1 = __expf(rB1);
        float wC0 = __expf(rC0), wC1 = __expf(rC1);
        float wD0 = __expf(rD0), wD1 = __expf(rD1);
        s0 += (wA0 + wB0) + (wC0 + wD0);
        s1 += (wA1 + wB1) + (wC1 + wD1);
        float wA = cpos < 8 ? wA0 : wA1;
        float wB = cpos < 8 ? wB0 : wB1;
        float wC = cpos < 8 ? wC0 : wC1;
        float wD = cpos < 8 ? wD0 : wD1;
        f16x8 hA = __builtin_bit_cast(f16x8, rhA);
        f16x8 hB = __builtin_bit_cast(f16x8, rhB);
        f16x8 hC = __builtin_bit_cast(f16x8, rhC);
        f16x8 hD = __builtin_bit_cast(f16x8, rhD);
#pragma unroll
        for (int k = 0; k < 8; ++k) {
            a[k] = fmaf((float)hA[k], wA, a[k]);
            a[k] = fmaf((float)hB[k], wB, a[k]);
            a[k] = fmaf((float)hC[k], wC, a[k]);
            a[k] = fmaf((float)hD[k], wD, a[k]);
        }
    }
    if (i + 1 < deg) {
        int siA = csr_src[start + i];
        int siB = csr_src[start + i + 1];
        float2 avA = *(const float2*)(asv + siA * 2);
        float2 avB = *(const float2*)(asv + siB * 2);
        uint4 rhA = *(const uint4*)(Hc + (long)siA * CDIM);
        uint4 rhB = *(const uint4*)(Hc + (long)siB * CDIM);
        float rA0 = avA.x + adn.x; rA0 = rA0 >= 0.f ? rA0 : NEG * rA0;
        float rA1 = avA.y + adn.y; rA1 = rA1 >= 0.f ? rA1 : NEG * rA1;
        float rB0 = avB.x + adn.x; rB0 = rB0 >= 0.f ? rB0 : NEG * rB0;
        float rB1 = avB.y + adn.y; rB1 = rB1 >= 0.f ? rB1 : NEG * rB1;
        float wA0 = __expf(rA0), wA1 = __expf(rA1);
        float wB0 = __expf(rB0), wB1 = __expf(rB1);
        s0 += wA0 + wB0; s1 += wA1 + wB1;
        float wA = cpos < 8 ? wA0 : wA1;
        float wB = cpos < 8 ? wB0 : wB1;
        f16x8 hA = __builtin_bit_cast(f16x8, rhA);
        f16x8 hB = __builtin_bit_cast(f16x8, rhB);
#pragma unroll
        for (int k = 0; k < 8; ++k) {
            a[k] = fmaf((float)hA[k], wA, a[k]);
            a[k] = fmaf((float)hB[k], wB, a[k]);
        }
        i += 2;
    }
    if (i < deg) {
        int si = csr_src[start + i];
        float2 av = *(const float2*)(asv + si * 2);
        uint4 rh = *(const uint4*)(Hc + (long)si * CDIM);
        float r0 = av.x + adn.x; r0 = r0 >= 0.f ? r0 : NEG * r0;
        float r1 = av.y + adn.y; r1 = r1 >= 0.f ? r1 : NEG * r1;
        float w0 = __expf(r0), w1 = __expf(r1);
        s0 += w0; s1 += w1;
        float wsel = cpos < 8 ? w0 : w1;
        f16x8 h = __builtin_bit_cast(f16x8, rh);
#pragma unroll
        for (int k = 0; k < 8; ++k) a[k] = fmaf((float)h[k], wsel, a[k]);
    }
    float ssel = cpos < 8 ? s0 : s1;
    float inv = ssel > 0.f ? 1.f / ssel : 0.f;
    uint4 o;
    o.x = (unsigned int)f2h(a[0] * inv) | ((unsigned int)f2h(a[1] * inv) << 16);
    o.y = (unsigned int)f2h(a[2] * inv) | ((unsigned int)f2h(a[3] * inv) << 16);
    o.z = (unsigned int)f2h(a[4] * inv) | ((unsigned int)f2h(a[5] * inv) << 16);
    o.w = (unsigned int)f2h(a[6] * inv) | ((unsigned int)f2h(a[7] * inv) << 16);
    *(uint4*)(Out + (long)node * CDIM + cpos * 8) = o;
}

// ---- final classifier with fused semantic combine (attn computed inline) ----
__global__ __launch_bounds__(256)
void final_linear_kernel(const unsigned short* __restrict__ O0,
                         const unsigned short* __restrict__ O1,
                         const float* __restrict__ saccp,
                         const float* __restrict__ lw, const float* __restrict__ lb,
                         float* __restrict__ out) {
    __shared__ float lws[CDIM * FOUT];
    int tid = threadIdx.x;
    for (int i = tid; i < CDIM * FOUT; i += 256) lws[i] = lw[i];
    __syncthreads();
    float fa0, fa1;
    attn_from_sacc(saccp, fa0, fa1);
    int idx = blockIdx.x * 256 + tid;
    if (idx >= NNODES * FOUT) return;
    int n = idx >> 3, o = idx & 7;
    const ushort8* r0 = (const ushort8*)(O0 + (long)n * CDIM);
    const ushort8* r1 = (const ushort8*)(O1 + (long)n * CDIM);
    float acc = lb[o];
#pragma unroll
    for (int k8 = 0; k8 < 16; ++k8) {
        ushort8 v0 = r0[k8];
        ushort8 v1 = r1[k8];
#pragma unroll
        for (int e = 0; e < 8; ++e) {
            float hv = fa0 * hrelu2f(v0[e]) + fa1 * hrelu2f(v1[e]);
            acc = fmaf(hv, lws[(k8 * 8 + e) * FOUT + o], acc);
        }
    }
    out[idx] = acc;
}

extern "C" void kernel_launch(void* const* d_in, const int* in_sizes, int n_in,
                              void* d_out, int out_size, void* d_ws, size_t ws_size,
                              hipStream_t stream) {
    const float* x          = (const float*)d_in[0];
    const int*   ei_spatial = (const int*)d_in[1];
    const int*   ei_similar = (const int*)d_in[2];
    const float* p1_proj_w  = (const float*)d_in[3];
    const float* p1_proj_b  = (const float*)d_in[4];
    const float* p1_att_src = (const float*)d_in[5];
    const float* p1_att_dst = (const float*)d_in[6];
    const float* p1_q       = (const float*)d_in[7];
    const float* p1_kw      = (const float*)d_in[8];
    const float* p1_kb      = (const float*)d_in[9];
    const float* p2_proj_w  = (const float*)d_in[10];
    const float* p2_proj_b  = (const float*)d_in[11];
    const float* p2_att_src = (const float*)d_in[12];
    const float* p2_att_dst = (const float*)d_in[13];
    const float* p2_q       = (const float*)d_in[14];
    const float* p2_kw      = (const float*)d_in[15];
    const float* p2_kb      = (const float*)d_in[16];
    const float* lin_w      = (const float*)d_in[17];
    const float* lin_b      = (const float*)d_in[18];

    float* ws = (float*)d_ws;
    const size_t nc = (size_t)NNODES * CDIM;
    const size_t nh2 = (size_t)NNODES * HHEADS;

    float* asrc = ws;                    // 2*N*H
    float* adst = asrc + 2 * nh2;        // 2*N*H
    float* sacc = adst + 2 * nh2;        // 4 (L1: [0..1], L2: [2..3])
    int* rowptr0 = (int*)(sacc + 4);     // N+1
    int* rowptr1 = rowptr0 + (NNODES + 1);
    int* rank0   = rowptr1 + (NNODES + 1);  // E
    int* rank1   = rank0 + EEDGES;          // E
    int* cs0     = rank1 + EEDGES;          // E
    int* cs1     = cs0 + EEDGES;            // E
    int* deg0    = cs1 + EEDGES;            // N (deg0/deg1 contiguous for one memset)
    int* deg1    = deg0 + NNODES;           // N
    int* bsum0   = deg1 + NNODES;           // SB
    int* bsum1   = bsum0 + SB;              // SB
    uintptr_t kp = (uintptr_t)(bsum1 + SB);
    kp = (kp + 15) & ~(uintptr_t)15;
    unsigned short* p1T = (unsigned short*)kp;      // FIN*CDIM f16
    unsigned short* k1T = p1T + FIN * CDIM;         // CDIM*CDIM
    unsigned short* p2T = k1T + CDIM * CDIM;        // CDIM*CDIM
    unsigned short* k2T = p2T + CDIM * CDIM;        // CDIM*CDIM
    unsigned short* Hb  = k2T + CDIM * CDIM;        // N*C f16
    unsigned short* O0b = Hb + nc;
    unsigned short* O1b = O0b + nc;

    const int gm = (NNODES + 63) / 64;      // 1563
    const int gseg = NNODES / 16;           // 6250 (exact)
    const int nh = NNODES * HHEADS;

    // ---- CSR build + weight cvt (hist & cvt overlapped; rank captured) ----
    hipMemsetAsync(deg0, 0, 2 * NNODES * sizeof(int), stream);
    hist_cvt<<<2 * GEB + CVB, 256, 0, stream>>>(
        ei_spatial + EEDGES, deg0, rank0, ei_similar + EEDGES, deg1, rank1,
        p1_proj_w, p1_kw, p2_proj_w, p2_kw, p1T, k1T, p2T, k2T, sacc);
    scan_partial_dual<<<2 * SB, 256, 0, stream>>>(deg0, bsum0, deg1, bsum1);
    scan_bsum_dual<<<1, 64, 0, stream>>>(bsum0, bsum1);
    scan_final_dual<<<2 * SB, 256, 0, stream>>>(deg0, bsum0, rowptr0,
                                                deg1, bsum1, rowptr1);
    fill_dual<<<2 * GEB, 256, 0, stream>>>(
        ei_spatial, ei_spatial + EEDGES, rank0, rowptr0, cs0,
        ei_similar, ei_similar + EEDGES, rank1, rowptr1, cs1);

    // ================= Layer 1 =================
    proj1_kernel<<<gm, 256, 0, stream>>>(x, p1T, p1_proj_b, p1_att_src, p1_att_dst,
                                         Hb, asrc, adst);
    seg_aggregate_dual<<<2 * gseg, 256, 0, stream>>>(
        rowptr0, cs0, asrc, adst, O0b,
        rowptr1, cs1, asrc + nh, adst + nh, O1b, Hb, gseg);
    score_mfma_dual<<<2 * SNB, 256, 0, stream>>>(O0b, O1b, k1T, p1_kb, p1_q, sacc);

    // ================= Layer 2 (combine + attn-softmax fused into proj) =================
    proj2_kernel<<<gm, 256, 0, stream>>>(O0b, O1b, sacc, p2T, p2_proj_b,
                                         p2_att_src, p2_att_dst, Hb, asrc, adst);
    seg_aggregate_dual<<<2 * gseg, 256, 0, stream>>>(
        rowptr0, cs0, asrc, adst, O0b,
        rowptr1, cs1, asrc + nh, adst + nh, O1b, Hb, gseg);
    score_mfma_dual<<<2 * SNB, 256, 0, stream>>>(O0b, O1b, k2T, p2_kb, p2_q, sacc + 2);

    // ================= Final classifier (combine + attn-softmax fused) =================
    const int gfin = (NNODES * FOUT + 255) / 256;
    final_linear_kernel<<<gfin, 256, 0, stream>>>(O0b, O1b, sacc + 2, lin_w, lin_b,
                                                  (float*)d_out);
}